// Round 1
// baseline (1927.312 us; speedup 1.0000x reference)
//
#include <hip/hip_runtime.h>
#include <math.h>

#define NB 8
#define NN 1024
#define NH 256
#define NL 3

constexpr int EPI_NONE = 0, EPI_BIAS = 1, EPI_BIAS_RELU = 2, EPI_BIAS_RELU_RESID = 3,
              EPI_BIAS_RESID = 4, EPI_EDIST = 5, EPI_SCORES = 6;

__device__ __forceinline__ float blockSum256(float v) {
    __shared__ float sm[4];
    #pragma unroll
    for (int o = 32; o; o >>= 1) v += __shfl_down(v, o, 64);
    int lane = threadIdx.x & 63, wid = threadIdx.x >> 6;
    if (lane == 0) sm[wid] = v;
    __syncthreads();
    if (threadIdx.x == 0) sm[0] = sm[0] + sm[1] + sm[2] + sm[3];
    __syncthreads();
    float r = sm[0];
    __syncthreads();
    return r;
}

__device__ __forceinline__ float blockMax256(float v) {
    __shared__ float sm[4];
    #pragma unroll
    for (int o = 32; o; o >>= 1) v = fmaxf(v, __shfl_down(v, o, 64));
    int lane = threadIdx.x & 63, wid = threadIdx.x >> 6;
    if (lane == 0) sm[wid] = v;
    __syncthreads();
    if (threadIdx.x == 0) sm[0] = fmaxf(fmaxf(sm[0], sm[1]), fmaxf(sm[2], sm[3]));
    __syncthreads();
    float r = sm[0];
    __syncthreads();
    return r;
}

// ---------------- tiled fp32 GEMM, 128x128 tile, BK=16, 256 thr, 8x8/thread ----
// C[M][Nc] = A @ B  (BT=false: B is KxNc row-major)  or  A @ B^T (BT=true: B is NcxK rows)
// grid = (Nc/128, M/128, batch)
template <bool BT, int EPI>
__global__ __launch_bounds__(256) void gemm_k(
    const float* __restrict__ A, int lda, long sA,
    const float* __restrict__ B, int ldb, long sB,
    float* __restrict__ C, int ldc, long sC,
    int K,
    const float* __restrict__ bias, long sBias,
    const float* __restrict__ resid, int ldr,
    const float* __restrict__ emat, int lde, long sE,
    float scale)
{
    __shared__ float As[16][132];
    __shared__ float Bs[16][132];
    const int tid = threadIdx.x;
    const int tx = tid & 15, ty = tid >> 4;
    const int z = blockIdx.z;
    const float* Ab = A + (long)z * sA;
    const float* Bb = B + (long)z * sB;
    float* Cb = C + (long)z * sC;
    const int row0 = blockIdx.y * 128, col0 = blockIdx.x * 128;

    float acc[8][8];
    #pragma unroll
    for (int i = 0; i < 8; i++)
        #pragma unroll
        for (int j = 0; j < 8; j++) acc[i][j] = 0.f;

    const int ar = tid >> 1;          // 0..127
    const int ak = (tid & 1) * 8;     // 0 or 8
    const int bn4 = (tid & 31) * 4;   // 0..124
    const int bk = tid >> 5;          // 0..7

    for (int k0 = 0; k0 < K; k0 += 16) {
        float4 a0 = *(const float4*)(Ab + (long)(row0 + ar) * lda + k0 + ak);
        float4 a1 = *(const float4*)(Ab + (long)(row0 + ar) * lda + k0 + ak + 4);
        As[ak + 0][ar] = a0.x; As[ak + 1][ar] = a0.y; As[ak + 2][ar] = a0.z; As[ak + 3][ar] = a0.w;
        As[ak + 4][ar] = a1.x; As[ak + 5][ar] = a1.y; As[ak + 6][ar] = a1.z; As[ak + 7][ar] = a1.w;
        if (BT) {
            float4 b0 = *(const float4*)(Bb + (long)(col0 + ar) * ldb + k0 + ak);
            float4 b1 = *(const float4*)(Bb + (long)(col0 + ar) * ldb + k0 + ak + 4);
            Bs[ak + 0][ar] = b0.x; Bs[ak + 1][ar] = b0.y; Bs[ak + 2][ar] = b0.z; Bs[ak + 3][ar] = b0.w;
            Bs[ak + 4][ar] = b1.x; Bs[ak + 5][ar] = b1.y; Bs[ak + 6][ar] = b1.z; Bs[ak + 7][ar] = b1.w;
        } else {
            #pragma unroll
            for (int r = 0; r < 2; r++) {
                int kk = r * 8 + bk;
                float4 bv = *(const float4*)(Bb + (long)(k0 + kk) * ldb + col0 + bn4);
                *(float4*)&Bs[kk][bn4] = bv;
            }
        }
        __syncthreads();
        #pragma unroll
        for (int kk = 0; kk < 16; kk++) {
            float4 aL = *(const float4*)&As[kk][ty * 4];
            float4 aH = *(const float4*)&As[kk][64 + ty * 4];
            float4 bL = *(const float4*)&Bs[kk][tx * 4];
            float4 bH = *(const float4*)&Bs[kk][64 + tx * 4];
            float a_[8] = {aL.x, aL.y, aL.z, aL.w, aH.x, aH.y, aH.z, aH.w};
            float b_[8] = {bL.x, bL.y, bL.z, bL.w, bH.x, bH.y, bH.z, bH.w};
            #pragma unroll
            for (int i = 0; i < 8; i++)
                #pragma unroll
                for (int j = 0; j < 8; j++)
                    acc[i][j] = fmaf(a_[i], b_[j], acc[i][j]);
        }
        __syncthreads();
    }

    #pragma unroll
    for (int i = 0; i < 8; i++) {
        int lr = (i < 4) ? (ty * 4 + i) : (64 + ty * 4 + i - 4);
        long r = row0 + lr;
        #pragma unroll
        for (int j = 0; j < 8; j++) {
            int lc = (j < 4) ? (tx * 4 + j) : (64 + tx * 4 + j - 4);
            long c = col0 + lc;
            float v = acc[i][j];
            if (EPI == EPI_BIAS) v += bias[c];
            else if (EPI == EPI_BIAS_RELU) v = fmaxf(v + bias[c], 0.f);
            else if (EPI == EPI_BIAS_RELU_RESID) v = fmaxf(v + bias[c], 0.f) + resid[r * ldr + c];
            else if (EPI == EPI_BIAS_RESID) v = v + bias[c] + resid[r * ldr + c];
            else if (EPI == EPI_EDIST) {
                const float* rnb = bias + (long)z * sBias;
                float d2 = fmaxf(rnb[r] + rnb[c] - 2.f * v, 0.f);
                v = expf(-sqrtf(d2));
            } else if (EPI == EPI_SCORES) {
                v = v * scale * emat[(long)z * sE + r * lde + c];
            }
            Cb[r * ldc + c] = v;
        }
    }
}

// base[b][j] = b_in[j] + sum_k relu(tf*w_time[k]+b_time[k]) * w_in[3+k][j]
__global__ __launch_bounds__(256) void base_k(const int* __restrict__ t,
                                              const float* __restrict__ w_time,
                                              const float* __restrict__ b_time,
                                              const float* __restrict__ w_in,
                                              const float* __restrict__ b_in,
                                              float* __restrict__ base) {
    int b = blockIdx.x, j = threadIdx.x;
    __shared__ float te[256];
    float tf = (float)t[b] / 200.0f;
    te[j] = fmaxf(tf * w_time[j] + b_time[j], 0.f);
    __syncthreads();
    float acc = b_in[j];
    for (int k = 0; k < 256; k++) acc = fmaf(te[k], w_in[(3 + k) * 256 + j], acc);
    base[b * 256 + j] = acc;
}

// h[row][j] = relu(x0*w0[j]+x1*w1[j]+x2*w2[j] + base[b][j]);  h3 = h[:, :3]
__global__ __launch_bounds__(256) void hinit_k(const float* __restrict__ x,
                                               const float* __restrict__ w_in,
                                               const float* __restrict__ base,
                                               float* __restrict__ h,
                                               float* __restrict__ h3) {
    long row = blockIdx.x;
    int b = (int)(row >> 10);
    int j = threadIdx.x;
    float x0 = x[row * 3 + 0], x1 = x[row * 3 + 1], x2 = x[row * 3 + 2];
    float v = base[b * 256 + j];
    v = fmaf(x0, w_in[j], v);
    v = fmaf(x1, w_in[256 + j], v);
    v = fmaf(x2, w_in[512 + j], v);
    v = fmaxf(v, 0.f);
    h[row * 256 + j] = v;
    if (j < 3) h3[row * 3 + j] = v;
}

// geo row + row sum-of-squares
__global__ __launch_bounds__(256) void geo_k(const float* __restrict__ h3,
                                             float* __restrict__ geo,
                                             float* __restrict__ rn) {
    int bi = blockIdx.x;
    int b = bi >> 10, i = bi & 1023;
    const float* hb = h3 + (long)b * NN * 3;
    float ax = hb[i * 3 + 0], ay = hb[i * 3 + 1], az = hb[i * 3 + 2];
    float* grow = geo + (long)bi * NN;
    float accs = 0.f;
    #pragma unroll
    for (int j0 = 0; j0 < NN; j0 += 256) {
        int j = j0 + threadIdx.x;
        float dx = hb[j * 3 + 0] - ax, dy = hb[j * 3 + 1] - ay, dz = hb[j * 3 + 2] - az;
        float d2 = dx * dx + dy * dy + dz * dz;
        float d = (d2 > 0.f) ? sqrtf(d2) : 0.f;
        grow[j] = d;
        accs += d2;
    }
    float tot = blockSum256(accs);
    if (threadIdx.x == 0) rn[bi] = tot;
}

__global__ __launch_bounds__(256) void softmax_k(float* __restrict__ S) {
    long row = blockIdx.x;
    float* p = S + row * NN;
    int t = threadIdx.x;
    float x0 = p[t], x1 = p[t + 256], x2 = p[t + 512], x3 = p[t + 768];
    float m = blockMax256(fmaxf(fmaxf(x0, x1), fmaxf(x2, x3)));
    float e0 = expf(x0 - m), e1 = expf(x1 - m), e2 = expf(x2 - m), e3 = expf(x3 - m);
    float s = blockSum256(e0 + e1 + e2 + e3);
    float inv = 1.f / s;
    p[t] = e0 * inv; p[t + 256] = e1 * inv; p[t + 512] = e2 * inv; p[t + 768] = e3 * inv;
}

__global__ __launch_bounds__(256) void ln_k(float* __restrict__ X,
                                            const float* __restrict__ g,
                                            const float* __restrict__ b) {
    long row = blockIdx.x;
    float* p = X + row * NH;
    int t = threadIdx.x;
    float v = p[t];
    float mu = blockSum256(v) * (1.f / NH);
    float d = v - mu;
    float var = blockSum256(d * d) * (1.f / NH);
    p[t] = d * rsqrtf(var + 1e-5f) * g[t] + b[t];
}

__global__ __launch_bounds__(256) void out_k(const float* __restrict__ h,
                                             const float* __restrict__ w_out,
                                             const float* __restrict__ b_out,
                                             float* __restrict__ out) {
    long row = blockIdx.x;
    int wid = threadIdx.x >> 6, lane = threadIdx.x & 63;
    if (wid < 3) {
        float acc = 0.f;
        for (int k = lane; k < 256; k += 64) acc = fmaf(h[row * 256 + k], w_out[k * 3 + wid], acc);
        #pragma unroll
        for (int o = 32; o; o >>= 1) acc += __shfl_down(acc, o, 64);
        if (lane == 0) out[row * 3 + wid] = acc + b_out[wid];
    }
}

extern "C" void kernel_launch(void* const* d_in, const int* in_sizes, int n_in,
                              void* d_out, int out_size, void* d_ws, size_t ws_size,
                              hipStream_t stream) {
    const float* x      = (const float*)d_in[0];
    const int*   t      = (const int*)  d_in[1];
    const float* w_time = (const float*)d_in[3];
    const float* b_time = (const float*)d_in[4];
    const float* w_in   = (const float*)d_in[5];
    const float* b_in   = (const float*)d_in[6];
    const float* w_out  = (const float*)d_in[7];
    const float* b_out  = (const float*)d_in[8];
    const float* qkv_w  = (const float*)d_in[9];
    const float* qkv_b  = (const float*)d_in[10];
    const float* ao_w   = (const float*)d_in[11];
    const float* ao_b   = (const float*)d_in[12];
    const float* fc1_w  = (const float*)d_in[13];
    const float* fc1_b  = (const float*)d_in[14];
    const float* fc2_w  = (const float*)d_in[15];
    const float* fc2_b  = (const float*)d_in[16];
    const float* ln1_g  = (const float*)d_in[17];
    const float* ln1_b  = (const float*)d_in[18];
    const float* ln2_g  = (const float*)d_in[19];
    const float* ln2_b  = (const float*)d_in[20];
    float* out = (float*)d_out;

    float* ws    = (float*)d_ws;
    float* h     = ws;                  // 2,097,152
    float* xb    = ws + 2097152;        // 2,097,152
    float* edist = ws + 4194304;        // 8,388,608
    float* sbuf  = ws + 12582912;       // 8,388,608  (geo, then scores each layer)
    float* qkvb  = ws + 20971520;       // 8,388,608  (qkv 6.29M, then f1 8.39M)
    float* obuf  = ws + 29360128;       // 2,097,152
    float* base  = ws + 31457280;       // 2048
    float* rn    = ws + 31459328;       // 8192
    float* h3    = ws + 31467520;       // 24576  -> total 31,492,096 floats (~126 MB)

    const float scale = 1.0f / 16.0f;  // 1/sqrt(256)

    base_k<<<NB, 256, 0, stream>>>(t, w_time, b_time, w_in, b_in, base);
    hinit_k<<<NB * NN, 256, 0, stream>>>(x, w_in, base, h, h3);
    geo_k<<<NB * NN, 256, 0, stream>>>(h3, sbuf, rn);
    // edist = exp(-cdist(geo, geo)), layer-invariant
    gemm_k<true, EPI_EDIST><<<dim3(8, 8, 8), 256, 0, stream>>>(
        sbuf, NN, (long)NN * NN, sbuf, NN, (long)NN * NN, edist, NN, (long)NN * NN,
        NN, rn, NN, nullptr, 0, nullptr, 0, 0, 0.f);

    for (int l = 0; l < NL; ++l) {
        // qkv = h @ qkv_w[l] + qkv_b[l]   (8192 x 768, K=256)
        gemm_k<false, EPI_BIAS><<<dim3(6, 64, 1), 256, 0, stream>>>(
            h, NH, 0, qkv_w + (long)l * NH * 768, 768, 0, qkvb, 768, 0,
            NH, qkv_b + l * 768, 0, nullptr, 0, nullptr, 0, 0, 0.f);
        // scores = (q @ k^T) * scale * edist    (batched 1024x1024, K=256)
        gemm_k<true, EPI_SCORES><<<dim3(8, 8, 8), 256, 0, stream>>>(
            qkvb, 768, (long)NN * 768, qkvb + 256, 768, (long)NN * 768,
            sbuf, NN, (long)NN * NN, NH, nullptr, 0, nullptr, 0,
            edist, NN, (long)NN * NN, scale);
        softmax_k<<<NB * NN, 256, 0, stream>>>(sbuf);
        // O = attn @ v    (batched 1024x256, K=1024)
        gemm_k<false, EPI_NONE><<<dim3(2, 8, 8), 256, 0, stream>>>(
            sbuf, NN, (long)NN * NN, qkvb + 512, 768, (long)NN * 768,
            obuf, NH, (long)NN * NH, NN, nullptr, 0, nullptr, 0, nullptr, 0, 0, 0.f);
        // xb = O @ ao_w[l] + ao_b[l] + h   (pre-LN1)
        gemm_k<false, EPI_BIAS_RESID><<<dim3(2, 64, 1), 256, 0, stream>>>(
            obuf, NH, 0, ao_w + (long)l * NH * NH, NH, 0, xb, NH, 0,
            NH, ao_b + l * NH, 0, h, NH, nullptr, 0, 0, 0.f);
        ln_k<<<NB * NN, 256, 0, stream>>>(xb, ln1_g + l * NH, ln1_b + l * NH);
        // f1 = relu(xb @ fc1_w[l] + fc1_b[l])   (8192 x 1024, K=256) -> qkvb region
        gemm_k<false, EPI_BIAS_RELU><<<dim3(8, 64, 1), 256, 0, stream>>>(
            xb, NH, 0, fc1_w + (long)l * NH * 1024, 1024, 0, qkvb, 1024, 0,
            NH, fc1_b + l * 1024, 0, nullptr, 0, nullptr, 0, 0, 0.f);
        // h = relu(f1 @ fc2_w[l] + fc2_b[l]) + xb   (pre-LN2)
        gemm_k<false, EPI_BIAS_RELU_RESID><<<dim3(2, 64, 1), 256, 0, stream>>>(
            qkvb, 1024, 0, fc2_w + (long)l * 1024 * NH, NH, 0, h, NH, 0,
            1024, fc2_b + l * NH, 0, xb, NH, nullptr, 0, 0, 0.f);
        ln_k<<<NB * NN, 256, 0, stream>>>(h, ln2_g + l * NH, ln2_b + l * NH);
    }
    out_k<<<NB * NN, 256, 0, stream>>>(h, w_out, b_out, out);
}

// Round 2
// 610.386 us; speedup vs baseline: 3.1575x; 3.1575x over previous
//
#include <hip/hip_runtime.h>
#include <math.h>

#define NB 8
#define NN 1024
#define NH 256
#define NL 3

typedef unsigned short u16;
typedef __bf16 bf16x8 __attribute__((ext_vector_type(8)));
typedef float f32x4 __attribute__((ext_vector_type(4)));

constexpr int EPI_NONE = 0, EPI_BIAS = 1, EPI_BIAS_RELU = 2, EPI_BIAS_RELU_RESID = 3,
              EPI_BIAS_RESID = 4, EPI_EDIST = 5, EPI_SCORES = 6;

__device__ __forceinline__ unsigned bf16rne(float f) {
    unsigned u = __float_as_uint(f);
    return (u + 0x7fffu + ((u >> 16) & 1u)) >> 16;
}
__device__ __forceinline__ unsigned bfpair(float a, float b) {
    return bf16rne(a) | (bf16rne(b) << 16);
}
__device__ __forceinline__ uint4 pack8(float4 x, float4 y) {
    uint4 r;
    r.x = bfpair(x.x, x.y); r.y = bfpair(x.z, x.w);
    r.z = bfpair(y.x, y.y); r.w = bfpair(y.z, y.w);
    return r;
}
__device__ __forceinline__ float bf2f(u16 h) {
    unsigned u = ((unsigned)h) << 16;
    return __uint_as_float(u);
}

__device__ __forceinline__ float blockSum256(float v) {
    __shared__ float sm[4];
    #pragma unroll
    for (int o = 32; o; o >>= 1) v += __shfl_down(v, o, 64);
    int lane = threadIdx.x & 63, wid = threadIdx.x >> 6;
    if (lane == 0) sm[wid] = v;
    __syncthreads();
    if (threadIdx.x == 0) sm[0] = sm[0] + sm[1] + sm[2] + sm[3];
    __syncthreads();
    float r = sm[0];
    __syncthreads();
    return r;
}

__device__ __forceinline__ float blockMax256(float v) {
    __shared__ float sm[4];
    #pragma unroll
    for (int o = 32; o; o >>= 1) v = fmaxf(v, __shfl_down(v, o, 64));
    int lane = threadIdx.x & 63, wid = threadIdx.x >> 6;
    if (lane == 0) sm[wid] = v;
    __syncthreads();
    if (threadIdx.x == 0) sm[0] = fmaxf(fmaxf(sm[0], sm[1]), fmaxf(sm[2], sm[3]));
    __syncthreads();
    float r = sm[0];
    __syncthreads();
    return r;
}

// ================= bf16 MFMA GEMM: 128x128 tile, BK=64, 256 thr (4 waves) ====
// C = A @ Bt^T.  A: MxK row-major (fp32, or bf16 if ABF). Bt: NxK row-major bf16.
// AUG (edist): K=3072 augmented [hi,hi,lo] x [hi,lo,hi] over a [.|1024-col-hi|1024-col-lo] buffer.
// grid = (N/128, M/128, batch)
template <int EPI, bool ABF, bool AUG, bool OBF>
__global__ __launch_bounds__(256) void gemm_mfma(
    const void* __restrict__ A, int lda, long sA,
    const u16* __restrict__ Bt, int ldb, long sB,
    void* __restrict__ C, int ldc, long sC,
    int K,
    const float* __restrict__ bias, long sBias,
    const float* __restrict__ resid, int ldr,
    const u16* __restrict__ emat, int lde, long sE,
    float scale)
{
    __shared__ uint4 sm4[2048];   // As: [0..1023] (128 rows x 8 chunks), Bs: [1024..2047]
    const int tid = threadIdx.x;
    const int z = blockIdx.z;
    const int row0 = blockIdx.y * 128, col0 = blockIdx.x * 128;

    f32x4 acc[4][4];
    #pragma unroll
    for (int m = 0; m < 4; m++)
        #pragma unroll
        for (int n = 0; n < 4; n++) acc[m][n] = (f32x4){0.f, 0.f, 0.f, 0.f};

    const int srow = tid >> 1;        // 0..127
    const int half = tid & 1;         // k-half (32 elements)
    const int cb = half * 4;          // chunk base
    const int swz = srow & 7;

    const int l = tid & 63, wid = tid >> 6;
    const int wr = wid >> 1, wc = wid & 1;
    const int lrow = l & 15, lgrp = l >> 4;

    for (int k0 = 0; k0 < K; k0 += 64) {
        int kk = k0, aOff = 0, bOff = 0;
        if (AUG) {
            int seg = k0 >> 10;
            kk = k0 & 1023;
            aOff = (seg == 2) ? 1024 : 0;
            bOff = (seg == 1) ? 1024 : 0;
        }
        uint4 ca0, ca1, ca2, ca3;
        if (ABF) {
            const u16* Ap = (const u16*)A + (long)z * sA + (long)(row0 + srow) * lda + kk + aOff + half * 32;
            ca0 = *(const uint4*)(Ap + 0);  ca1 = *(const uint4*)(Ap + 8);
            ca2 = *(const uint4*)(Ap + 16); ca3 = *(const uint4*)(Ap + 24);
        } else {
            const float* Ap = (const float*)A + (long)z * sA + (long)(row0 + srow) * lda + kk + half * 32;
            float4 f0 = *(const float4*)(Ap + 0),  f1 = *(const float4*)(Ap + 4);
            float4 f2 = *(const float4*)(Ap + 8),  f3 = *(const float4*)(Ap + 12);
            float4 f4 = *(const float4*)(Ap + 16), f5 = *(const float4*)(Ap + 20);
            float4 f6 = *(const float4*)(Ap + 24), f7 = *(const float4*)(Ap + 28);
            ca0 = pack8(f0, f1); ca1 = pack8(f2, f3); ca2 = pack8(f4, f5); ca3 = pack8(f6, f7);
        }
        const u16* Bp = Bt + (long)z * sB + (long)(col0 + srow) * ldb + kk + bOff + half * 32;
        uint4 cb0 = *(const uint4*)(Bp + 0),  cb1 = *(const uint4*)(Bp + 8);
        uint4 cb2 = *(const uint4*)(Bp + 16), cb3 = *(const uint4*)(Bp + 24);

        sm4[srow * 8 + ((cb + 0) ^ swz)] = ca0;
        sm4[srow * 8 + ((cb + 1) ^ swz)] = ca1;
        sm4[srow * 8 + ((cb + 2) ^ swz)] = ca2;
        sm4[srow * 8 + ((cb + 3) ^ swz)] = ca3;
        sm4[1024 + srow * 8 + ((cb + 0) ^ swz)] = cb0;
        sm4[1024 + srow * 8 + ((cb + 1) ^ swz)] = cb1;
        sm4[1024 + srow * 8 + ((cb + 2) ^ swz)] = cb2;
        sm4[1024 + srow * 8 + ((cb + 3) ^ swz)] = cb3;
        __syncthreads();

        #pragma unroll
        for (int ks = 0; ks < 2; ks++) {
            int c = ks * 4 + lgrp;   // 16B chunk index along k
            bf16x8 a[4], b[4];
            #pragma unroll
            for (int m = 0; m < 4; m++) {
                int r = wr * 64 + m * 16 + lrow;
                a[m] = __builtin_bit_cast(bf16x8, sm4[r * 8 + (c ^ (r & 7))]);
            }
            #pragma unroll
            for (int n = 0; n < 4; n++) {
                int r = wc * 64 + n * 16 + lrow;
                b[n] = __builtin_bit_cast(bf16x8, sm4[1024 + r * 8 + (c ^ (r & 7))]);
            }
            #pragma unroll
            for (int m = 0; m < 4; m++)
                #pragma unroll
                for (int n = 0; n < 4; n++)
                    acc[m][n] = __builtin_amdgcn_mfma_f32_16x16x32_bf16(a[m], b[n], acc[m][n], 0, 0, 0);
        }
        __syncthreads();
    }

    // epilogue: C/D layout col = lane&15, row = 4*(lane>>4)+reg  [m89-verified]
    const float* rnb = (EPI == EPI_EDIST) ? (bias + (long)z * sBias) : nullptr;
    #pragma unroll
    for (int m = 0; m < 4; m++) {
        #pragma unroll
        for (int n = 0; n < 4; n++) {
            int rbase = row0 + wr * 64 + m * 16 + lgrp * 4;
            int cc = col0 + wc * 64 + n * 16 + lrow;
            float bv = 0.f;
            if (EPI == EPI_BIAS || EPI == EPI_BIAS_RELU || EPI == EPI_BIAS_RELU_RESID || EPI == EPI_BIAS_RESID)
                bv = bias[cc];
            #pragma unroll
            for (int reg = 0; reg < 4; reg++) {
                long r = rbase + reg;
                float v = acc[m][n][reg];
                if (EPI == EPI_BIAS) v += bv;
                else if (EPI == EPI_BIAS_RELU) v = fmaxf(v + bv, 0.f);
                else if (EPI == EPI_BIAS_RELU_RESID) v = fmaxf(v + bv, 0.f) + resid[r * ldr + cc];
                else if (EPI == EPI_BIAS_RESID) v = v + bv + resid[r * ldr + cc];
                else if (EPI == EPI_EDIST) {
                    float d2 = fmaxf(rnb[r] + rnb[cc] - 2.f * v, 0.f);
                    v = expf(-sqrtf(d2));
                } else if (EPI == EPI_SCORES) {
                    v = v * scale * bf2f(emat[(long)z * sE + r * (long)lde + cc]);
                }
                if (OBF) ((u16*)C)[(long)z * sC + r * ldc + cc] = (u16)bf16rne(v);
                else     ((float*)C)[(long)z * sC + r * ldc + cc] = v;
            }
        }
    }
}

// base[b][j] = b_in[j] + sum_k relu(tf*w_time[k]+b_time[k]) * w_in[3+k][j]
__global__ __launch_bounds__(256) void base_k(const int* __restrict__ t,
                                              const float* __restrict__ w_time,
                                              const float* __restrict__ b_time,
                                              const float* __restrict__ w_in,
                                              const float* __restrict__ b_in,
                                              float* __restrict__ base) {
    int b = blockIdx.x, j = threadIdx.x;
    __shared__ float te[256];
    float tf = (float)t[b] / 200.0f;
    te[j] = fmaxf(tf * w_time[j] + b_time[j], 0.f);
    __syncthreads();
    float acc = b_in[j];
    for (int k = 0; k < 256; k++) acc = fmaf(te[k], w_in[(3 + k) * 256 + j], acc);
    base[b * 256 + j] = acc;
}

__global__ __launch_bounds__(256) void hinit_k(const float* __restrict__ x,
                                               const float* __restrict__ w_in,
                                               const float* __restrict__ base,
                                               float* __restrict__ h,
                                               float* __restrict__ h3) {
    long row = blockIdx.x;
    int b = (int)(row >> 10);
    int j = threadIdx.x;
    float x0 = x[row * 3 + 0], x1 = x[row * 3 + 1], x2 = x[row * 3 + 2];
    float v = base[b * 256 + j];
    v = fmaf(x0, w_in[j], v);
    v = fmaf(x1, w_in[256 + j], v);
    v = fmaf(x2, w_in[512 + j], v);
    v = fmaxf(v, 0.f);
    h[row * 256 + j] = v;
    if (j < 3) h3[row * 3 + j] = v;
}

// geo row -> hi/lo bf16 split into ghl[bi][0..1023 | 1024..2047], rn = sum(rep^2)
__global__ __launch_bounds__(256) void geo_k(const float* __restrict__ h3,
                                             u16* __restrict__ ghl,
                                             float* __restrict__ rn) {
    int bi = blockIdx.x;
    int b = bi >> 10, i = bi & 1023;
    const float* hb = h3 + (long)b * NN * 3;
    float ax = hb[i * 3 + 0], ay = hb[i * 3 + 1], az = hb[i * 3 + 2];
    u16* grow = ghl + (long)bi * 2048;
    float accs = 0.f;
    #pragma unroll
    for (int j0 = 0; j0 < NN; j0 += 256) {
        int j = j0 + threadIdx.x;
        float dx = hb[j * 3 + 0] - ax, dy = hb[j * 3 + 1] - ay, dz = hb[j * 3 + 2] - az;
        float d2 = dx * dx + dy * dy + dz * dz;
        float d = (d2 > 0.f) ? sqrtf(d2) : 0.f;
        u16 hi = (u16)bf16rne(d);
        float fhi = bf2f(hi);
        u16 lo = (u16)bf16rne(d - fhi);
        float rep = fhi + bf2f(lo);
        grow[j] = hi;
        grow[1024 + j] = lo;
        accs += rep * rep;
    }
    float tot = blockSum256(accs);
    if (threadIdx.x == 0) rn[bi] = tot;
}

// transpose+cast all layer weights to bf16 (NxK "Bt" layout)
__global__ __launch_bounds__(256) void wtrans_k(const float* __restrict__ qkv_w,
                                                const float* __restrict__ ao_w,
                                                const float* __restrict__ fc1_w,
                                                const float* __restrict__ fc2_w,
                                                u16* __restrict__ qkv_wt,
                                                u16* __restrict__ ao_wt,
                                                u16* __restrict__ fc1_wt,
                                                u16* __restrict__ fc2_wt) {
    int type = blockIdx.z, lyr = blockIdx.y;
    int R, Cc;
    const float* src;
    u16* dst;
    if (type == 0) { R = 256; Cc = 768;  src = qkv_w + (long)lyr * R * Cc; dst = qkv_wt + (long)lyr * R * Cc; }
    else if (type == 1) { R = 256; Cc = 256; src = ao_w + (long)lyr * R * Cc; dst = ao_wt + (long)lyr * R * Cc; }
    else if (type == 2) { R = 256; Cc = 1024; src = fc1_w + (long)lyr * R * Cc; dst = fc1_wt + (long)lyr * R * Cc; }
    else { R = 1024; Cc = 256; src = fc2_w + (long)lyr * R * Cc; dst = fc2_wt + (long)lyr * R * Cc; }
    int tC = Cc >> 5, tR = R >> 5;
    int tile = blockIdx.x;
    if (tile >= tC * tR) return;
    int c0 = (tile % tC) << 5, r0 = (tile / tC) << 5;
    __shared__ float tf[32][33];
    int tx = threadIdx.x & 31, ty = threadIdx.x >> 5;
    #pragma unroll
    for (int i = 0; i < 4; i++) {
        int r = ty + 8 * i;
        tf[r][tx] = src[(long)(r0 + r) * Cc + c0 + tx];
    }
    __syncthreads();
    #pragma unroll
    for (int i = 0; i < 4; i++) {
        int c = ty + 8 * i;
        dst[(long)(c0 + c) * R + r0 + tx] = (u16)bf16rne(tf[tx][c]);
    }
}

// transpose v (bf16, stride 768 within qkv) -> vt[b][c][n] bf16
__global__ __launch_bounds__(256) void vtrans_k(const u16* __restrict__ v, u16* __restrict__ vt) {
    int b = blockIdx.z;
    int n0 = blockIdx.x << 5, c0 = blockIdx.y << 5;
    const u16* vb = v + (long)b * NN * 768;
    u16* vtb = vt + (long)b * NH * NN;
    __shared__ u16 tile[32][33];
    int tx = threadIdx.x & 31, ty = threadIdx.x >> 5;
    #pragma unroll
    for (int i = 0; i < 4; i++) {
        int n = ty + 8 * i;
        tile[n][tx] = vb[(long)(n0 + n) * 768 + c0 + tx];
    }
    __syncthreads();
    #pragma unroll
    for (int i = 0; i < 4; i++) {
        int c = ty + 8 * i;
        vtb[(long)(c0 + c) * NN + n0 + tx] = tile[tx][c];
    }
}

__global__ __launch_bounds__(256) void softmax_k(float* __restrict__ S) {
    long row = blockIdx.x;
    float* p = S + row * NN;
    int t = threadIdx.x;
    float x0 = p[t], x1 = p[t + 256], x2 = p[t + 512], x3 = p[t + 768];
    float m = blockMax256(fmaxf(fmaxf(x0, x1), fmaxf(x2, x3)));
    float e0 = expf(x0 - m), e1 = expf(x1 - m), e2 = expf(x2 - m), e3 = expf(x3 - m);
    float s = blockSum256(e0 + e1 + e2 + e3);
    float inv = 1.f / s;
    p[t] = e0 * inv; p[t + 256] = e1 * inv; p[t + 512] = e2 * inv; p[t + 768] = e3 * inv;
}

__global__ __launch_bounds__(256) void ln_k(float* __restrict__ X,
                                            const float* __restrict__ g,
                                            const float* __restrict__ b) {
    long row = blockIdx.x;
    float* p = X + row * NH;
    int t = threadIdx.x;
    float v = p[t];
    float mu = blockSum256(v) * (1.f / NH);
    float d = v - mu;
    float var = blockSum256(d * d) * (1.f / NH);
    p[t] = d * rsqrtf(var + 1e-5f) * g[t] + b[t];
}

__global__ __launch_bounds__(256) void out_k(const float* __restrict__ h,
                                             const float* __restrict__ w_out,
                                             const float* __restrict__ b_out,
                                             float* __restrict__ out) {
    long row = blockIdx.x;
    int wid = threadIdx.x >> 6, lane = threadIdx.x & 63;
    if (wid < 3) {
        float acc = 0.f;
        for (int k = lane; k < 256; k += 64) acc = fmaf(h[row * 256 + k], w_out[k * 3 + wid], acc);
        #pragma unroll
        for (int o = 32; o; o >>= 1) acc += __shfl_down(acc, o, 64);
        if (lane == 0) out[row * 3 + wid] = acc + b_out[wid];
    }
}

extern "C" void kernel_launch(void* const* d_in, const int* in_sizes, int n_in,
                              void* d_out, int out_size, void* d_ws, size_t ws_size,
                              hipStream_t stream) {
    const float* x      = (const float*)d_in[0];
    const int*   t      = (const int*)  d_in[1];
    const float* w_time = (const float*)d_in[3];
    const float* b_time = (const float*)d_in[4];
    const float* w_in   = (const float*)d_in[5];
    const float* b_in   = (const float*)d_in[6];
    const float* w_out  = (const float*)d_in[7];
    const float* b_out  = (const float*)d_in[8];
    const float* qkv_w  = (const float*)d_in[9];
    const float* qkv_b  = (const float*)d_in[10];
    const float* ao_w   = (const float*)d_in[11];
    const float* ao_b   = (const float*)d_in[12];
    const float* fc1_w  = (const float*)d_in[13];
    const float* fc1_b  = (const float*)d_in[14];
    const float* fc2_w  = (const float*)d_in[15];
    const float* fc2_b  = (const float*)d_in[16];
    const float* ln1_g  = (const float*)d_in[17];
    const float* ln1_b  = (const float*)d_in[18];
    const float* ln2_g  = (const float*)d_in[19];
    const float* ln2_b  = (const float*)d_in[20];
    float* out = (float*)d_out;

    char* W = (char*)d_ws;
    float* h     = (float*)(W);                          // 8 MB
    float* xb    = (float*)(W + (8ul << 20));            // 8 MB
    float* obuf  = (float*)(W + (16ul << 20));           // 8 MB
    float* sbuf  = (float*)(W + (24ul << 20));           // 32 MB (scores/attn fp32)
    u16*   edist = (u16*)  (W + (56ul << 20));           // 16 MB bf16
    u16*   ghl   = (u16*)  (W + (72ul << 20));           // 32 MB bf16 (hi|lo), freed after edist
    u16*   qkvb  = (u16*)  (W + (72ul << 20));           // 12 MB bf16 (aliases ghl)
    u16*   f1    = (u16*)  (W + (84ul << 20));           // 16 MB bf16
    u16*   vt    = (u16*)  (W + (104ul << 20));          // 4 MB bf16
    u16*   wts   = (u16*)  (W + (108ul << 20));          // 4.5 MB bf16
    u16* qkv_wt = wts;                // 3 * 196608
    u16* ao_wt  = wts + 589824;       // 3 * 65536
    u16* fc1_wt = wts + 786432;       // 3 * 262144
    u16* fc2_wt = wts + 1572864;      // 3 * 262144
    float* base = (float*)(W + (114ul << 20));
    float* rn   = base + 2048;
    float* h3   = rn + 8192;

    const float scale = 1.0f / 16.0f;

    base_k<<<NB, 256, 0, stream>>>(t, w_time, b_time, w_in, b_in, base);
    hinit_k<<<NB * NN, 256, 0, stream>>>(x, w_in, base, h, h3);
    geo_k<<<NB * NN, 256, 0, stream>>>(h3, ghl, rn);
    wtrans_k<<<dim3(256, NL, 4), 256, 0, stream>>>(qkv_w, ao_w, fc1_w, fc2_w,
                                                   qkv_wt, ao_wt, fc1_wt, fc2_wt);
    // edist = exp(-cdist(geo,geo)) via augmented hi/lo GEMM, K=3072, out bf16
    gemm_mfma<EPI_EDIST, true, true, true><<<dim3(8, 8, 8), 256, 0, stream>>>(
        ghl, 2048, (long)NN * 2048, ghl, 2048, (long)NN * 2048,
        edist, NN, (long)NN * NN, 3072, rn, NN, nullptr, 0, nullptr, 0, 0, 0.f);

    for (int l = 0; l < NL; ++l) {
        // qkv (bf16 out): h @ qkv_wt[l]^T
        gemm_mfma<EPI_BIAS, false, false, true><<<dim3(6, 64, 1), 256, 0, stream>>>(
            h, NH, 0, qkv_wt + (long)l * 196608, NH, 0, qkvb, 768, 0,
            NH, qkv_b + l * 768, 0, nullptr, 0, nullptr, 0, 0, 0.f);
        vtrans_k<<<dim3(32, 8, NB), 256, 0, stream>>>(qkvb + 512, vt);
        // scores = (q @ k^T) * scale * edist  (fp32 out)
        gemm_mfma<EPI_SCORES, true, false, false><<<dim3(8, 8, 8), 256, 0, stream>>>(
            qkvb, 768, (long)NN * 768, qkvb + 256, 768, (long)NN * 768,
            sbuf, NN, (long)NN * NN, NH, nullptr, 0, nullptr, 0,
            edist, NN, (long)NN * NN, scale);
        softmax_k<<<NB * NN, 256, 0, stream>>>(sbuf);
        // O = attn @ vt^T
        gemm_mfma<EPI_NONE, false, false, false><<<dim3(2, 8, 8), 256, 0, stream>>>(
            sbuf, NN, (long)NN * NN, vt, NN, (long)NH * NN,
            obuf, NH, (long)NN * NH, NN, nullptr, 0, nullptr, 0, nullptr, 0, 0, 0.f);
        // xb = O @ ao_wt^T + ao_b + h
        gemm_mfma<EPI_BIAS_RESID, false, false, false><<<dim3(2, 64, 1), 256, 0, stream>>>(
            obuf, NH, 0, ao_wt + (long)l * 65536, NH, 0, xb, NH, 0,
            NH, ao_b + l * NH, 0, h, NH, nullptr, 0, 0, 0.f);
        ln_k<<<NB * NN, 256, 0, stream>>>(xb, ln1_g + l * NH, ln1_b + l * NH);
        // f1 = relu(xb @ fc1_wt^T + b)  (bf16 out)
        gemm_mfma<EPI_BIAS_RELU, false, false, true><<<dim3(8, 64, 1), 256, 0, stream>>>(
            xb, NH, 0, fc1_wt + (long)l * 262144, NH, 0, f1, 1024, 0,
            NH, fc1_b + l * 1024, 0, nullptr, 0, nullptr, 0, 0, 0.f);
        // h = relu(f1 @ fc2_wt^T + b) + xb
        gemm_mfma<EPI_BIAS_RELU_RESID, true, false, false><<<dim3(2, 64, 1), 256, 0, stream>>>(
            f1, 1024, 0, fc2_wt + (long)l * 262144, 1024, 0, h, NH, 0,
            1024, fc2_b + l * NH, 0, xb, NH, nullptr, 0, 0, 0.f);
        ln_k<<<NB * NN, 256, 0, stream>>>(h, ln2_g + l * NH, ln2_b + l * NH);
    }
    out_k<<<NB * NN, 256, 0, stream>>>(h, w_out, b_out, out);
}

// Round 3
// 522.462 us; speedup vs baseline: 3.6889x; 1.1683x over previous
//
#include <hip/hip_runtime.h>
#include <math.h>

#define NB 8
#define NN 1024
#define NH 256
#define NL 3

typedef unsigned short u16;
typedef __bf16 bf16x8 __attribute__((ext_vector_type(8)));
typedef float f32x4 __attribute__((ext_vector_type(4)));

constexpr int EPI_NONE = 0, EPI_BIAS = 1, EPI_BIAS_RELU = 2, EPI_BIAS_RELU_RESID = 3,
              EPI_BIAS_RESID = 4, EPI_EDIST = 5, EPI_SCORES_E = 6, EPI_PVDIV = 7;

__device__ __forceinline__ unsigned bf16rne(float f) {
    unsigned u = __float_as_uint(f);
    return (u + 0x7fffu + ((u >> 16) & 1u)) >> 16;
}
__device__ __forceinline__ unsigned bfpair(float a, float b) {
    return bf16rne(a) | (bf16rne(b) << 16);
}
__device__ __forceinline__ uint4 pack8(float4 x, float4 y) {
    uint4 r;
    r.x = bfpair(x.x, x.y); r.y = bfpair(x.z, x.w);
    r.z = bfpair(y.x, y.y); r.w = bfpair(y.z, y.w);
    return r;
}
__device__ __forceinline__ float bf2f(u16 h) {
    unsigned u = ((unsigned)h) << 16;
    return __uint_as_float(u);
}

__device__ __forceinline__ float blockSum256(float v) {
    __shared__ float sm[4];
    #pragma unroll
    for (int o = 32; o; o >>= 1) v += __shfl_down(v, o, 64);
    int lane = threadIdx.x & 63, wid = threadIdx.x >> 6;
    if (lane == 0) sm[wid] = v;
    __syncthreads();
    if (threadIdx.x == 0) sm[0] = sm[0] + sm[1] + sm[2] + sm[3];
    __syncthreads();
    float r = sm[0];
    __syncthreads();
    return r;
}

// ================= bf16 MFMA GEMM: 128x128 tile, BK=64, 256 thr (4 waves) ====
// C = A @ Bt^T.  A: MxK row-major (fp32, or bf16 if ABF). Bt: NxK row-major bf16.
// SWZ: 0 none, 1 batch-pin (lid%8 -> batch, same XCD), 2 chunked (m157) for z=1 grids.
template <int EPI, bool ABF, bool AUG, bool OBF, int SWZ>
__global__ __launch_bounds__(256) void gemm_mfma(
    const void* __restrict__ A, int lda, long sA,
    const u16* __restrict__ Bt, int ldb, long sB,
    void* __restrict__ C, int ldc, long sC,
    int K,
    const float* __restrict__ bias, long sBias,
    const float* __restrict__ resid, int ldr,
    const u16* __restrict__ emat, int lde, long sE,
    float scale, float* __restrict__ aux)
{
    __shared__ uint4 sm4[2048];   // As: [0..1023], Bs: [1024..2047]
    const int tid = threadIdx.x;

    int bx = blockIdx.x, by = blockIdx.y, bz = blockIdx.z;
    if (SWZ == 1) {
        int gx = gridDim.x, gy = gridDim.y;
        int lid = bx + gx * (by + gy * bz);
        bz = lid & 7;
        int rest = lid >> 3;
        bx = rest % gx; by = rest / gx;
    } else if (SWZ == 2) {
        int gx = gridDim.x;
        int T = gx * gridDim.y;
        int lid = bx + gx * by;
        int nl = (lid & 7) * (T >> 3) + (lid >> 3);
        bx = nl % gx; by = nl / gx;
    }
    const int z = bz;
    const int row0 = by * 128, col0 = bx * 128;

    f32x4 acc[4][4];
    #pragma unroll
    for (int m = 0; m < 4; m++)
        #pragma unroll
        for (int n = 0; n < 4; n++) acc[m][n] = (f32x4){0.f, 0.f, 0.f, 0.f};

    const int srow = tid >> 1;        // 0..127
    const int half = tid & 1;         // k-half (32 elements)
    const int cb = half * 4;          // chunk base
    const int swz = srow & 7;

    const int l = tid & 63, wid = tid >> 6;
    const int wr = wid >> 1, wc = wid & 1;
    const int lrow = l & 15, lgrp = l >> 4;

    for (int k0 = 0; k0 < K; k0 += 64) {
        int kk = k0, aOff = 0, bOff = 0;
        if (AUG) {
            int seg = k0 >> 10;
            kk = k0 & 1023;
            aOff = (seg == 2) ? 1024 : 0;
            bOff = (seg == 1) ? 1024 : 0;
        }
        uint4 ca0, ca1, ca2, ca3;
        if (ABF) {
            const u16* Ap = (const u16*)A + (long)z * sA + (long)(row0 + srow) * lda + kk + aOff + half * 32;
            ca0 = *(const uint4*)(Ap + 0);  ca1 = *(const uint4*)(Ap + 8);
            ca2 = *(const uint4*)(Ap + 16); ca3 = *(const uint4*)(Ap + 24);
        } else {
            const float* Ap = (const float*)A + (long)z * sA + (long)(row0 + srow) * lda + kk + half * 32;
            float4 f0 = *(const float4*)(Ap + 0),  f1 = *(const float4*)(Ap + 4);
            float4 f2 = *(const float4*)(Ap + 8),  f3 = *(const float4*)(Ap + 12);
            float4 f4 = *(const float4*)(Ap + 16), f5 = *(const float4*)(Ap + 20);
            float4 f6 = *(const float4*)(Ap + 24), f7 = *(const float4*)(Ap + 28);
            ca0 = pack8(f0, f1); ca1 = pack8(f2, f3); ca2 = pack8(f4, f5); ca3 = pack8(f6, f7);
        }
        const u16* Bp = Bt + (long)z * sB + (long)(col0 + srow) * ldb + kk + bOff + half * 32;
        uint4 cb0 = *(const uint4*)(Bp + 0),  cb1 = *(const uint4*)(Bp + 8);
        uint4 cb2 = *(const uint4*)(Bp + 16), cb3 = *(const uint4*)(Bp + 24);

        sm4[srow * 8 + ((cb + 0) ^ swz)] = ca0;
        sm4[srow * 8 + ((cb + 1) ^ swz)] = ca1;
        sm4[srow * 8 + ((cb + 2) ^ swz)] = ca2;
        sm4[srow * 8 + ((cb + 3) ^ swz)] = ca3;
        sm4[1024 + srow * 8 + ((cb + 0) ^ swz)] = cb0;
        sm4[1024 + srow * 8 + ((cb + 1) ^ swz)] = cb1;
        sm4[1024 + srow * 8 + ((cb + 2) ^ swz)] = cb2;
        sm4[1024 + srow * 8 + ((cb + 3) ^ swz)] = cb3;
        __syncthreads();

        #pragma unroll
        for (int ks = 0; ks < 2; ks++) {
            int c = ks * 4 + lgrp;
            bf16x8 a[4], b[4];
            #pragma unroll
            for (int m = 0; m < 4; m++) {
                int r = wr * 64 + m * 16 + lrow;
                a[m] = __builtin_bit_cast(bf16x8, sm4[r * 8 + (c ^ (r & 7))]);
            }
            #pragma unroll
            for (int n = 0; n < 4; n++) {
                int r = wc * 64 + n * 16 + lrow;
                b[n] = __builtin_bit_cast(bf16x8, sm4[1024 + r * 8 + (c ^ (r & 7))]);
            }
            #pragma unroll
            for (int m = 0; m < 4; m++)
                #pragma unroll
                for (int n = 0; n < 4; n++)
                    acc[m][n] = __builtin_amdgcn_mfma_f32_16x16x32_bf16(a[m], b[n], acc[m][n], 0, 0, 0);
        }
        __syncthreads();
    }

    // epilogue: C/D layout col = lane&15, row = 4*(lane>>4)+reg
    if (EPI == EPI_SCORES_E) {
        // E = exp(qk*scale*edist) (bf16), per-tile row sums -> aux[(z*8+bx)*1024 + qrow]
        float rowsum[4][4];
        #pragma unroll
        for (int m = 0; m < 4; m++)
            #pragma unroll
            for (int g = 0; g < 4; g++) rowsum[m][g] = 0.f;
        const u16* eb = emat + (long)z * sE;
        #pragma unroll
        for (int m = 0; m < 4; m++) {
            int rbase = row0 + wr * 64 + m * 16 + lgrp * 4;
            #pragma unroll
            for (int n = 0; n < 4; n++) {
                int cc = col0 + wc * 64 + n * 16 + lrow;
                #pragma unroll
                for (int reg = 0; reg < 4; reg++) {
                    long r = rbase + reg;
                    float v = acc[m][n][reg] * scale * bf2f(eb[r * (long)lde + cc]);
                    float e = expf(v);
                    rowsum[m][reg] += e;
                    ((u16*)C)[(long)z * sC + r * ldc + cc] = (u16)bf16rne(e);
                }
            }
        }
        #pragma unroll
        for (int m = 0; m < 4; m++)
            #pragma unroll
            for (int reg = 0; reg < 4; reg++) {
                float s = rowsum[m][reg];
                s += __shfl_xor(s, 1); s += __shfl_xor(s, 2);
                s += __shfl_xor(s, 4); s += __shfl_xor(s, 8);
                rowsum[m][reg] = s;
            }
        float* psum = (float*)sm4;   // [128][2]
        if (lrow == 0) {
            #pragma unroll
            for (int m = 0; m < 4; m++)
                #pragma unroll
                for (int reg = 0; reg < 4; reg++) {
                    int lr = wr * 64 + m * 16 + lgrp * 4 + reg;
                    psum[lr * 2 + wc] = rowsum[m][reg];
                }
        }
        __syncthreads();
        if (wc == 0 && lrow == 0) {
            #pragma unroll
            for (int m = 0; m < 4; m++)
                #pragma unroll
                for (int reg = 0; reg < 4; reg++) {
                    int lr = wr * 64 + m * 16 + lgrp * 4 + reg;
                    aux[((long)z * 8 + bx) * 1024 + row0 + lr] = psum[lr * 2] + psum[lr * 2 + 1];
                }
        }
        return;
    }

    #pragma unroll
    for (int m = 0; m < 4; m++) {
        #pragma unroll
        for (int n = 0; n < 4; n++) {
            int rbase = row0 + wr * 64 + m * 16 + lgrp * 4;
            int cc = col0 + wc * 64 + n * 16 + lrow;
            float bv = 0.f;
            if (EPI == EPI_BIAS || EPI == EPI_BIAS_RELU || EPI == EPI_BIAS_RELU_RESID || EPI == EPI_BIAS_RESID)
                bv = bias[cc];
            #pragma unroll
            for (int reg = 0; reg < 4; reg++) {
                long r = rbase + reg;
                float v = acc[m][n][reg];
                if (EPI == EPI_BIAS) v += bv;
                else if (EPI == EPI_BIAS_RELU) v = fmaxf(v + bv, 0.f);
                else if (EPI == EPI_BIAS_RELU_RESID) v = fmaxf(v + bv, 0.f) + resid[r * ldr + cc];
                else if (EPI == EPI_BIAS_RESID) v = v + bv + resid[r * ldr + cc];
                else if (EPI == EPI_EDIST) {
                    const float* rnb = bias + (long)z * sBias;
                    float d2 = fmaxf(rnb[r] + rnb[cc] - 2.f * v, 0.f);
                    v = expf(-sqrtf(d2));
                } else if (EPI == EPI_PVDIV) {
                    v = v * aux[(long)z * 1024 + r];
                }
                if (OBF) ((u16*)C)[(long)z * sC + r * ldc + cc] = (u16)bf16rne(v);
                else     ((float*)C)[(long)z * sC + r * ldc + cc] = v;
            }
        }
    }
}

__global__ __launch_bounds__(256) void fin_k(const float* __restrict__ ps,
                                             float* __restrict__ invL) {
    int r = blockIdx.x * 256 + threadIdx.x;   // 0..8191
    int b = r >> 10, q = r & 1023;
    float s = 0.f;
    #pragma unroll
    for (int t = 0; t < 8; t++) s += ps[((long)b * 8 + t) * 1024 + q];
    invL[r] = 1.f / s;
}

__global__ __launch_bounds__(256) void base_k(const int* __restrict__ t,
                                              const float* __restrict__ w_time,
                                              const float* __restrict__ b_time,
                                              const float* __restrict__ w_in,
                                              const float* __restrict__ b_in,
                                              float* __restrict__ base) {
    int b = blockIdx.x, j = threadIdx.x;
    __shared__ float te[256];
    float tf = (float)t[b] / 200.0f;
    te[j] = fmaxf(tf * w_time[j] + b_time[j], 0.f);
    __syncthreads();
    float acc = b_in[j];
    for (int k = 0; k < 256; k++) acc = fmaf(te[k], w_in[(3 + k) * 256 + j], acc);
    base[b * 256 + j] = acc;
}

__global__ __launch_bounds__(256) void hinit_k(const float* __restrict__ x,
                                               const float* __restrict__ w_in,
                                               const float* __restrict__ base,
                                               float* __restrict__ h,
                                               float* __restrict__ h3) {
    long row = blockIdx.x;
    int b = (int)(row >> 10);
    int j = threadIdx.x;
    float x0 = x[row * 3 + 0], x1 = x[row * 3 + 1], x2 = x[row * 3 + 2];
    float v = base[b * 256 + j];
    v = fmaf(x0, w_in[j], v);
    v = fmaf(x1, w_in[256 + j], v);
    v = fmaf(x2, w_in[512 + j], v);
    v = fmaxf(v, 0.f);
    h[row * 256 + j] = v;
    if (j < 3) h3[row * 3 + j] = v;
}

// geo row -> hi/lo bf16 split, rn = sum(rep^2)
__global__ __launch_bounds__(256) void geo_k(const float* __restrict__ h3,
                                             u16* __restrict__ ghl,
                                             float* __restrict__ rn) {
    int bi = blockIdx.x;
    int b = bi >> 10, i = bi & 1023;
    const float* hb = h3 + (long)b * NN * 3;
    float ax = hb[i * 3 + 0], ay = hb[i * 3 + 1], az = hb[i * 3 + 2];
    u16* grow = ghl + (long)bi * 2048;
    float accs = 0.f;
    #pragma unroll
    for (int j0 = 0; j0 < NN; j0 += 256) {
        int j = j0 + threadIdx.x;
        float dx = hb[j * 3 + 0] - ax, dy = hb[j * 3 + 1] - ay, dz = hb[j * 3 + 2] - az;
        float d2 = dx * dx + dy * dy + dz * dz;
        float d = (d2 > 0.f) ? sqrtf(d2) : 0.f;
        u16 hi = (u16)bf16rne(d);
        float fhi = bf2f(hi);
        u16 lo = (u16)bf16rne(d - fhi);
        float rep = fhi + bf2f(lo);
        grow[j] = hi;
        grow[1024 + j] = lo;
        accs += rep * rep;
    }
    float tot = blockSum256(accs);
    if (threadIdx.x == 0) rn[bi] = tot;
}

// transpose+cast all layer weights to bf16 (NxK "Bt" layout)
__global__ __launch_bounds__(256) void wtrans_k(const float* __restrict__ qkv_w,
                                                const float* __restrict__ ao_w,
                                                const float* __restrict__ fc1_w,
                                                const float* __restrict__ fc2_w,
                                                u16* __restrict__ qkv_wt,
                                                u16* __restrict__ ao_wt,
                                                u16* __restrict__ fc1_wt,
                                                u16* __restrict__ fc2_wt) {
    int type = blockIdx.z, lyr = blockIdx.y;
    int R, Cc;
    const float* src;
    u16* dst;
    if (type == 0) { R = 256; Cc = 768;  src = qkv_w + (long)lyr * R * Cc; dst = qkv_wt + (long)lyr * R * Cc; }
    else if (type == 1) { R = 256; Cc = 256; src = ao_w + (long)lyr * R * Cc; dst = ao_wt + (long)lyr * R * Cc; }
    else if (type == 2) { R = 256; Cc = 1024; src = fc1_w + (long)lyr * R * Cc; dst = fc1_wt + (long)lyr * R * Cc; }
    else { R = 1024; Cc = 256; src = fc2_w + (long)lyr * R * Cc; dst = fc2_wt + (long)lyr * R * Cc; }
    int tC = Cc >> 5, tR = R >> 5;
    int tile = blockIdx.x;
    if (tile >= tC * tR) return;
    int c0 = (tile % tC) << 5, r0 = (tile / tC) << 5;
    __shared__ float tf[32][33];
    int tx = threadIdx.x & 31, ty = threadIdx.x >> 5;
    #pragma unroll
    for (int i = 0; i < 4; i++) {
        int r = ty + 8 * i;
        tf[r][tx] = src[(long)(r0 + r) * Cc + c0 + tx];
    }
    __syncthreads();
    #pragma unroll
    for (int i = 0; i < 4; i++) {
        int c = ty + 8 * i;
        dst[(long)(c0 + c) * R + r0 + tx] = (u16)bf16rne(tf[tx][c]);
    }
}

// transpose v (bf16, stride 768 within qkv) -> vt[b][c][n] bf16
__global__ __launch_bounds__(256) void vtrans_k(const u16* __restrict__ v, u16* __restrict__ vt) {
    int b = blockIdx.z;
    int n0 = blockIdx.x << 5, c0 = blockIdx.y << 5;
    const u16* vb = v + (long)b * NN * 768;
    u16* vtb = vt + (long)b * NH * NN;
    __shared__ u16 tile[32][33];
    int tx = threadIdx.x & 31, ty = threadIdx.x >> 5;
    #pragma unroll
    for (int i = 0; i < 4; i++) {
        int n = ty + 8 * i;
        tile[n][tx] = vb[(long)(n0 + n) * 768 + c0 + tx];
    }
    __syncthreads();
    #pragma unroll
    for (int i = 0; i < 4; i++) {
        int c = ty + 8 * i;
        vtb[(long)(c0 + c) * NN + n0 + tx] = tile[tx][c];
    }
}

__global__ __launch_bounds__(256) void ln_k(float* __restrict__ X,
                                            const float* __restrict__ g,
                                            const float* __restrict__ b) {
    long row = blockIdx.x;
    float* p = X + row * NH;
    int t = threadIdx.x;
    float v = p[t];
    float mu = blockSum256(v) * (1.f / NH);
    float d = v - mu;
    float var = blockSum256(d * d) * (1.f / NH);
    p[t] = d * rsqrtf(var + 1e-5f) * g[t] + b[t];
}

__global__ __launch_bounds__(256) void out_k(const float* __restrict__ h,
                                             const float* __restrict__ w_out,
                                             const float* __restrict__ b_out,
                                             float* __restrict__ out) {
    long row = blockIdx.x;
    int wid = threadIdx.x >> 6, lane = threadIdx.x & 63;
    if (wid < 3) {
        float acc = 0.f;
        for (int k = lane; k < 256; k += 64) acc = fmaf(h[row * 256 + k], w_out[k * 3 + wid], acc);
        #pragma unroll
        for (int o = 32; o; o >>= 1) acc += __shfl_down(acc, o, 64);
        if (lane == 0) out[row * 3 + wid] = acc + b_out[wid];
    }
}

extern "C" void kernel_launch(void* const* d_in, const int* in_sizes, int n_in,
                              void* d_out, int out_size, void* d_ws, size_t ws_size,
                              hipStream_t stream) {
    const float* x      = (const float*)d_in[0];
    const int*   t      = (const int*)  d_in[1];
    const float* w_time = (const float*)d_in[3];
    const float* b_time = (const float*)d_in[4];
    const float* w_in   = (const float*)d_in[5];
    const float* b_in   = (const float*)d_in[6];
    const float* w_out  = (const float*)d_in[7];
    const float* b_out  = (const float*)d_in[8];
    const float* qkv_w  = (const float*)d_in[9];
    const float* qkv_b  = (const float*)d_in[10];
    const float* ao_w   = (const float*)d_in[11];
    const float* ao_b   = (const float*)d_in[12];
    const float* fc1_w  = (const float*)d_in[13];
    const float* fc1_b  = (const float*)d_in[14];
    const float* fc2_w  = (const float*)d_in[15];
    const float* fc2_b  = (const float*)d_in[16];
    const float* ln1_g  = (const float*)d_in[17];
    const float* ln1_b  = (const float*)d_in[18];
    const float* ln2_g  = (const float*)d_in[19];
    const float* ln2_b  = (const float*)d_in[20];
    float* out = (float*)d_out;

    char* W = (char*)d_ws;
    float* h     = (float*)(W);                          // 8 MB
    float* xb    = (float*)(W + (8ul << 20));            // 8 MB
    float* obuf  = (float*)(W + (16ul << 20));           // 8 MB
    u16*   E     = (u16*)  (W + (24ul << 20));           // 16 MB bf16 (exp-scores)
    u16*   edist = (u16*)  (W + (56ul << 20));           // 16 MB bf16
    u16*   ghl   = (u16*)  (W + (72ul << 20));           // 32 MB bf16 (hi|lo), freed after edist
    u16*   qkvb  = (u16*)  (W + (72ul << 20));           // 12 MB bf16 (aliases ghl)
    u16*   f1    = (u16*)  (W + (84ul << 20));           // 16 MB bf16
    u16*   vt    = (u16*)  (W + (104ul << 20));          // 4 MB bf16
    u16*   wts   = (u16*)  (W + (108ul << 20));          // 4.5 MB bf16
    u16* qkv_wt = wts;                // 3 * 196608
    u16* ao_wt  = wts + 589824;       // 3 * 65536
    u16* fc1_wt = wts + 786432;       // 3 * 262144
    u16* fc2_wt = wts + 1572864;      // 3 * 262144
    float* base = (float*)(W + (114ul << 20));
    float* rn   = base + 2048;
    float* h3   = rn + 8192;
    float* ps   = h3 + 24576;         // 8*8*1024 = 65536 floats
    float* invL = ps + 65536;         // 8192 floats

    const float scale = 1.0f / 16.0f;

    base_k<<<NB, 256, 0, stream>>>(t, w_time, b_time, w_in, b_in, base);
    hinit_k<<<NB * NN, 256, 0, stream>>>(x, w_in, base, h, h3);
    geo_k<<<NB * NN, 256, 0, stream>>>(h3, ghl, rn);
    wtrans_k<<<dim3(256, NL, 4), 256, 0, stream>>>(qkv_w, ao_w, fc1_w, fc2_w,
                                                   qkv_wt, ao_wt, fc1_wt, fc2_wt);
    // edist = exp(-cdist(geo,geo)) via augmented hi/lo GEMM, K=3072, out bf16
    gemm_mfma<EPI_EDIST, true, true, true, 1><<<dim3(8, 8, 8), 256, 0, stream>>>(
        ghl, 2048, (long)NN * 2048, ghl, 2048, (long)NN * 2048,
        edist, NN, (long)NN * NN, 3072, rn, NN, nullptr, 0, nullptr, 0, 0, 0.f, nullptr);

    for (int l = 0; l < NL; ++l) {
        // qkv (bf16 out): h @ qkv_wt[l]^T
        gemm_mfma<EPI_BIAS, false, false, true, 2><<<dim3(6, 64, 1), 256, 0, stream>>>(
            h, NH, 0, qkv_wt + (long)l * 196608, NH, 0, qkvb, 768, 0,
            NH, qkv_b + l * 768, 0, nullptr, 0, nullptr, 0, 0, 0.f, nullptr);
        vtrans_k<<<dim3(32, 8, NB), 256, 0, stream>>>(qkvb + 512, vt);
        // E = exp(q@k^T * scale * edist) (bf16) + per-tile row sums
        gemm_mfma<EPI_SCORES_E, true, false, true, 1><<<dim3(8, 8, 8), 256, 0, stream>>>(
            qkvb, 768, (long)NN * 768, qkvb + 256, 768, (long)NN * 768,
            E, NN, (long)NN * NN, NH, nullptr, 0, nullptr, 0,
            edist, NN, (long)NN * NN, scale, ps);
        fin_k<<<32, 256, 0, stream>>>(ps, invL);
        // O = (E @ vt^T) * invL[row]
        gemm_mfma<EPI_PVDIV, true, false, false, 1><<<dim3(2, 8, 8), 256, 0, stream>>>(
            E, NN, (long)NN * NN, vt, NN, (long)NH * NN,
            obuf, NH, (long)NN * NH, NN, nullptr, 0, nullptr, 0, nullptr, 0, 0, 0.f, invL);
        // xb = O @ ao_wt^T + ao_b + h
        gemm_mfma<EPI_BIAS_RESID, false, false, false, 2><<<dim3(2, 64, 1), 256, 0, stream>>>(
            obuf, NH, 0, ao_wt + (long)l * 65536, NH, 0, xb, NH, 0,
            NH, ao_b + l * NH, 0, h, NH, nullptr, 0, 0, 0.f, nullptr);
        ln_k<<<NB * NN, 256, 0, stream>>>(xb, ln1_g + l * NH, ln1_b + l * NH);
        // f1 = relu(xb @ fc1_wt^T + b)  (bf16 out)
        gemm_mfma<EPI_BIAS_RELU, false, false, true, 2><<<dim3(8, 64, 1), 256, 0, stream>>>(
            xb, NH, 0, fc1_wt + (long)l * 262144, NH, 0, f1, 1024, 0,
            NH, fc1_b + l * 1024, 0, nullptr, 0, nullptr, 0, 0, 0.f, nullptr);
        // h = relu(f1 @ fc2_wt^T + b) + xb
        gemm_mfma<EPI_BIAS_RELU_RESID, true, false, false, 2><<<dim3(2, 64, 1), 256, 0, stream>>>(
            f1, 1024, 0, fc2_wt + (long)l * 262144, 1024, 0, h, NH, 0,
            1024, fc2_b + l * NH, 0, xb, NH, nullptr, 0, 0, 0.f, nullptr);
        ln_k<<<NB * NN, 256, 0, stream>>>(h, ln2_g + l * NH, ln2_b + l * NH);
    }
    out_k<<<NB * NN, 256, 0, stream>>>(h, w_out, b_out, out);
}

// Round 4
// 478.015 us; speedup vs baseline: 4.0319x; 1.0930x over previous
//
#include <hip/hip_runtime.h>
#include <math.h>

#define NB 8
#define NN 1024
#define NH 256
#define NL 3

typedef unsigned short u16;
typedef __bf16 bf16x8 __attribute__((ext_vector_type(8)));
typedef float f32x4 __attribute__((ext_vector_type(4)));

constexpr int EPI_BIAS = 1, EPI_BIAS_RELU = 2, EPI_BIAS_RELU_RESID = 3,
              EPI_BIAS_RESID = 4, EPI_EDIST = 5;

__device__ __forceinline__ unsigned bf16rne(float f) {
    unsigned u = __float_as_uint(f);
    return (u + 0x7fffu + ((u >> 16) & 1u)) >> 16;
}
__device__ __forceinline__ unsigned bfpair(float a, float b) {
    return bf16rne(a) | (bf16rne(b) << 16);
}
__device__ __forceinline__ uint4 pack8(float4 x, float4 y) {
    uint4 r;
    r.x = bfpair(x.x, x.y); r.y = bfpair(x.z, x.w);
    r.z = bfpair(y.x, y.y); r.w = bfpair(y.z, y.w);
    return r;
}
__device__ __forceinline__ float bf2f(u16 h) {
    unsigned u = ((unsigned)h) << 16;
    return __uint_as_float(u);
}

__device__ __forceinline__ float blockSum256(float v) {
    __shared__ float sm[4];
    #pragma unroll
    for (int o = 32; o; o >>= 1) v += __shfl_down(v, o, 64);
    int lane = threadIdx.x & 63, wid = threadIdx.x >> 6;
    if (lane == 0) sm[wid] = v;
    __syncthreads();
    if (threadIdx.x == 0) sm[0] = sm[0] + sm[1] + sm[2] + sm[3];
    __syncthreads();
    float r = sm[0];
    __syncthreads();
    return r;
}

// ================= bf16 MFMA GEMM: 128x128 tile, BK=64, 256 thr (4 waves) ====
// C = A @ Bt^T.  A: MxK row-major (fp32, or bf16 if ABF). Bt: NxK row-major bf16.
// SWZ: 1 batch-pin (lid%8->batch), 2 chunked (z=1 grids), 3 triangular-symmetric
//      batch-pinned (edist: grid (36,1,8), writes transposed tile too).
template <int EPI, bool ABF, bool AUG, bool OBF, int SWZ>
__global__ __launch_bounds__(256) void gemm_mfma(
    const void* __restrict__ A, int lda, long sA,
    const u16* __restrict__ Bt, int ldb, long sB,
    void* __restrict__ C, int ldc, long sC,
    int K,
    const float* __restrict__ bias, long sBias,
    const float* __restrict__ resid, int ldr)
{
    __shared__ uint4 sm4[2048];   // As: [0..1023], Bs: [1024..2047]
    const int tid = threadIdx.x;

    int bx = blockIdx.x, by = blockIdx.y, bz = blockIdx.z;
    if (SWZ == 1) {
        int gx = gridDim.x, gy = gridDim.y;
        int lid = bx + gx * (by + gy * bz);
        bz = lid & 7;
        int rest = lid >> 3;
        bx = rest % gx; by = rest / gx;
    } else if (SWZ == 2) {
        int gx = gridDim.x;
        int T = gx * gridDim.y;
        int lid = bx + gx * by;
        int nl = (lid & 7) * (T >> 3) + (lid >> 3);
        bx = nl % gx; by = nl / gx;
    } else if (SWZ == 3) {
        int lid = bx + gridDim.x * bz;   // grid (36,1,8)
        bz = lid & 7;
        int idx = lid >> 3;              // 0..35 triangular
        by = (int)((sqrtf(8.f * (float)idx + 1.f) - 1.f) * 0.5f);
        bx = idx - (by * (by + 1)) / 2;
        if (bx > by) { by++; bx = idx - (by * (by + 1)) / 2; }
    }
    const int z = bz;
    const int row0 = by * 128, col0 = bx * 128;

    f32x4 acc[4][4];
    #pragma unroll
    for (int m = 0; m < 4; m++)
        #pragma unroll
        for (int n = 0; n < 4; n++) acc[m][n] = (f32x4){0.f, 0.f, 0.f, 0.f};

    const int srow = tid >> 1;        // 0..127
    const int half = tid & 1;         // k-half (32 elements)
    const int cb = half * 4;          // chunk base
    const int swz = srow & 7;

    const int l = tid & 63, wid = tid >> 6;
    const int wr = wid >> 1, wc = wid & 1;
    const int lrow = l & 15, lgrp = l >> 4;

    for (int k0 = 0; k0 < K; k0 += 64) {
        int kk = k0, aOff = 0, bOff = 0;
        if (AUG) {
            int seg = k0 >> 10;
            kk = k0 & 1023;
            aOff = (seg == 2) ? 1024 : 0;
            bOff = (seg == 1) ? 1024 : 0;
        }
        uint4 ca0, ca1, ca2, ca3;
        if (ABF) {
            const u16* Ap = (const u16*)A + (long)z * sA + (long)(row0 + srow) * lda + kk + aOff + half * 32;
            ca0 = *(const uint4*)(Ap + 0);  ca1 = *(const uint4*)(Ap + 8);
            ca2 = *(const uint4*)(Ap + 16); ca3 = *(const uint4*)(Ap + 24);
        } else {
            const float* Ap = (const float*)A + (long)z * sA + (long)(row0 + srow) * lda + kk + half * 32;
            float4 f0 = *(const float4*)(Ap + 0),  f1 = *(const float4*)(Ap + 4);
            float4 f2 = *(const float4*)(Ap + 8),  f3 = *(const float4*)(Ap + 12);
            float4 f4 = *(const float4*)(Ap + 16), f5 = *(const float4*)(Ap + 20);
            float4 f6 = *(const float4*)(Ap + 24), f7 = *(const float4*)(Ap + 28);
            ca0 = pack8(f0, f1); ca1 = pack8(f2, f3); ca2 = pack8(f4, f5); ca3 = pack8(f6, f7);
        }
        const u16* Bp = Bt + (long)z * sB + (long)(col0 + srow) * ldb + kk + bOff + half * 32;
        uint4 cb0 = *(const uint4*)(Bp + 0),  cb1 = *(const uint4*)(Bp + 8);
        uint4 cb2 = *(const uint4*)(Bp + 16), cb3 = *(const uint4*)(Bp + 24);

        sm4[srow * 8 + ((cb + 0) ^ swz)] = ca0;
        sm4[srow * 8 + ((cb + 1) ^ swz)] = ca1;
        sm4[srow * 8 + ((cb + 2) ^ swz)] = ca2;
        sm4[srow * 8 + ((cb + 3) ^ swz)] = ca3;
        sm4[1024 + srow * 8 + ((cb + 0) ^ swz)] = cb0;
        sm4[1024 + srow * 8 + ((cb + 1) ^ swz)] = cb1;
        sm4[1024 + srow * 8 + ((cb + 2) ^ swz)] = cb2;
        sm4[1024 + srow * 8 + ((cb + 3) ^ swz)] = cb3;
        __syncthreads();

        #pragma unroll
        for (int ks = 0; ks < 2; ks++) {
            int c = ks * 4 + lgrp;
            bf16x8 a[4], b[4];
            #pragma unroll
            for (int m = 0; m < 4; m++) {
                int r = wr * 64 + m * 16 + lrow;
                a[m] = __builtin_bit_cast(bf16x8, sm4[r * 8 + (c ^ (r & 7))]);
            }
            #pragma unroll
            for (int n = 0; n < 4; n++) {
                int r = wc * 64 + n * 16 + lrow;
                b[n] = __builtin_bit_cast(bf16x8, sm4[1024 + r * 8 + (c ^ (r & 7))]);
            }
            #pragma unroll
            for (int m = 0; m < 4; m++)
                #pragma unroll
                for (int n = 0; n < 4; n++)
                    acc[m][n] = __builtin_amdgcn_mfma_f32_16x16x32_bf16(a[m], b[n], acc[m][n], 0, 0, 0);
        }
        __syncthreads();
    }

    // epilogue: C/D layout col = lane&15, row = 4*(lane>>4)+reg
    #pragma unroll
    for (int m = 0; m < 4; m++) {
        #pragma unroll
        for (int n = 0; n < 4; n++) {
            int rbase = row0 + wr * 64 + m * 16 + lgrp * 4;
            int cc = col0 + wc * 64 + n * 16 + lrow;
            float bv = 0.f;
            if (EPI == EPI_BIAS || EPI == EPI_BIAS_RELU || EPI == EPI_BIAS_RELU_RESID || EPI == EPI_BIAS_RESID)
                bv = bias[cc];
            float vals[4];
            #pragma unroll
            for (int reg = 0; reg < 4; reg++) {
                long r = rbase + reg;
                float v = acc[m][n][reg];
                if (EPI == EPI_BIAS) v += bv;
                else if (EPI == EPI_BIAS_RELU) v = fmaxf(v + bv, 0.f);
                else if (EPI == EPI_BIAS_RELU_RESID) v = fmaxf(v + bv, 0.f) + resid[r * ldr + cc];
                else if (EPI == EPI_BIAS_RESID) v = v + bv + resid[r * ldr + cc];
                else if (EPI == EPI_EDIST) {
                    const float* rnb = bias + (long)z * sBias;
                    float d2 = fmaxf(rnb[r] + rnb[cc] - 2.f * v, 0.f);
                    v = expf(-sqrtf(d2));
                }
                vals[reg] = v;
                if (OBF) ((u16*)C)[(long)z * sC + r * ldc + cc] = (u16)bf16rne(v);
                else     ((float*)C)[(long)z * sC + r * ldc + cc] = v;
            }
            if (SWZ == 3 && bx != by) {
                // also write transposed tile (symmetric matrix): 4 u16 packed
                uint2 tv;
                tv.x = bfpair(vals[0], vals[1]);
                tv.y = bfpair(vals[2], vals[3]);
                *(uint2*)&((u16*)C)[(long)z * sC + (long)cc * ldc + rbase] = tv;
            }
        }
    }
}

// ============ flash attention: QBLK=32, KCHUNK=128, 512 thr (8 waves) ========
// O[b][q][c] = softmax-free normalized sum: exp(qk*scale*edist) @ V / rowsum
__global__ __launch_bounds__(512) void flash_k(
    const u16* __restrict__ qkv,    // [b][1024][768] bf16 (q +0, k +256)
    const u16* __restrict__ vt,     // [b][256][1024] bf16
    const u16* __restrict__ edist,  // [b][1024][1024] bf16
    u16* __restrict__ obuf,         // [b][1024][256] bf16
    float scale)
{
    __shared__ uint4 Ks[128][32];        // 64 KB, chunk ^ (row&7)
    __shared__ uint4 Vts[256][16];       // 64 KB, (ch&8)|((ch&7)^(c&7))
    __shared__ __align__(16) u16 Es[32][136];   // 8.7 KB edist tile
    __shared__ __align__(16) u16 Ps[32][136];   // 8.7 KB P tile
    __shared__ float rs[32][8];

    const int tid = threadIdx.x;
    const int l = tid & 63, w = tid >> 6;       // wave 0..7
    const int g = l >> 4, lr = l & 15;

    int lid = blockIdx.x + gridDim.x * blockIdx.y;   // grid (32, 8)
    const int b = lid & 7;           // batch pinned to XCD
    const int q0 = (lid >> 3) * 32;

    const u16* qkvb = qkv + (long)b * NN * 768;
    const u16* vtb  = vt + (long)b * NH * NN;
    const u16* eb   = edist + (long)b * NN * NN;

    // Q fragments in registers: row = q0+16m+lr, k = 32ks+8g
    uint4 qf[2][8];
    #pragma unroll
    for (int m = 0; m < 2; m++)
        #pragma unroll
        for (int ks = 0; ks < 8; ks++)
            qf[m][ks] = *(const uint4*)(qkvb + (long)(q0 + 16 * m + lr) * 768 + 32 * ks + 8 * g);

    f32x4 oacc[2][2];
    #pragma unroll
    for (int m = 0; m < 2; m++)
        #pragma unroll
        for (int nf = 0; nf < 2; nf++) oacc[m][nf] = (f32x4){0.f, 0.f, 0.f, 0.f};
    float rsum[2][4] = {{0.f, 0.f, 0.f, 0.f}, {0.f, 0.f, 0.f, 0.f}};

    for (int n0 = 0; n0 < NN; n0 += 128) {
        // stage K chunk (128 keys x 256)
        #pragma unroll
        for (int i = 0; i < 8; i++) {
            int idx = tid + 512 * i;
            int row = idx >> 5, ch = idx & 31;
            Ks[row][ch ^ (row & 7)] = *(const uint4*)(qkvb + (long)(n0 + row) * 768 + 256 + ch * 8);
        }
        // stage Vt chunk (256 c x 128 keys)
        #pragma unroll
        for (int i = 0; i < 8; i++) {
            int idx = tid + 512 * i;
            int c = idx >> 4, ch = idx & 15;
            Vts[c][(ch & 8) | ((ch & 7) ^ (c & 7))] = *(const uint4*)(vtb + (long)c * NN + n0 + ch * 8);
        }
        // stage edist tile (32 q x 128 keys)
        {
            int r = tid >> 4, ch = tid & 15;
            *(uint4*)&Es[r][ch * 8] = *(const uint4*)(eb + (long)(q0 + r) * NN + n0 + ch * 8);
        }
        __syncthreads();

        // S = Q @ K^T for this wave's 16 keys
        f32x4 s[2];
        s[0] = (f32x4){0.f, 0.f, 0.f, 0.f};
        s[1] = (f32x4){0.f, 0.f, 0.f, 0.f};
        const int krow = w * 16 + lr;
        #pragma unroll
        for (int ks = 0; ks < 8; ks++) {
            bf16x8 kf = __builtin_bit_cast(bf16x8, Ks[krow][(4 * ks + g) ^ (krow & 7)]);
            s[0] = __builtin_amdgcn_mfma_f32_16x16x32_bf16(__builtin_bit_cast(bf16x8, qf[0][ks]), kf, s[0], 0, 0, 0);
            s[1] = __builtin_amdgcn_mfma_f32_16x16x32_bf16(__builtin_bit_cast(bf16x8, qf[1][ks]), kf, s[1], 0, 0, 0);
        }
        // P = exp(S*scale*E), write to Ps, accumulate row sums
        #pragma unroll
        for (int m = 0; m < 2; m++)
            #pragma unroll
            for (int reg = 0; reg < 4; reg++) {
                int q = 16 * m + 4 * g + reg;
                int kc = w * 16 + lr;
                float p = expf(s[m][reg] * scale * bf2f(Es[q][kc]));
                rsum[m][reg] += p;
                Ps[q][kc] = (u16)bf16rne(p);
            }
        __syncthreads();
        // O += P @ V : A=Ps rows q, B=Vts rows c (wave owns 32 c-cols)
        #pragma unroll
        for (int ks = 0; ks < 4; ks++) {
            bf16x8 pa[2], vb[2];
            #pragma unroll
            for (int m = 0; m < 2; m++)
                pa[m] = __builtin_bit_cast(bf16x8, *(const uint4*)&Ps[16 * m + lr][32 * ks + 8 * g]);
            #pragma unroll
            for (int nf = 0; nf < 2; nf++) {
                int c = w * 32 + nf * 16 + lr;
                int ch = 4 * ks + g;
                vb[nf] = __builtin_bit_cast(bf16x8, Vts[c][(ch & 8) | ((ch & 7) ^ (c & 7))]);
            }
            #pragma unroll
            for (int m = 0; m < 2; m++)
                #pragma unroll
                for (int nf = 0; nf < 2; nf++)
                    oacc[m][nf] = __builtin_amdgcn_mfma_f32_16x16x32_bf16(pa[m], vb[nf], oacc[m][nf], 0, 0, 0);
        }
        __syncthreads();
    }

    // cross-lane (16-group) + cross-wave row-sum reduction
    #pragma unroll
    for (int m = 0; m < 2; m++)
        #pragma unroll
        for (int reg = 0; reg < 4; reg++) {
            float v = rsum[m][reg];
            v += __shfl_xor(v, 1); v += __shfl_xor(v, 2);
            v += __shfl_xor(v, 4); v += __shfl_xor(v, 8);
            rsum[m][reg] = v;
        }
    if (lr == 0) {
        #pragma unroll
        for (int m = 0; m < 2; m++)
            #pragma unroll
            for (int reg = 0; reg < 4; reg++)
                rs[16 * m + 4 * g + reg][w] = rsum[m][reg];
    }
    __syncthreads();
    #pragma unroll
    for (int m = 0; m < 2; m++) {
        #pragma unroll
        for (int reg = 0; reg < 4; reg++) {
            int q = 16 * m + 4 * g + reg;
            float t = 0.f;
            #pragma unroll
            for (int j = 0; j < 8; j++) t += rs[q][j];
            float inv = 1.f / t;
            #pragma unroll
            for (int nf = 0; nf < 2; nf++) {
                int c = w * 32 + nf * 16 + lr;
                obuf[(long)b * NN * NH + (long)(q0 + q) * NH + c] = (u16)bf16rne(oacc[m][nf][reg] * inv);
            }
        }
    }
}

__global__ __launch_bounds__(256) void base_k(const int* __restrict__ t,
                                              const float* __restrict__ w_time,
                                              const float* __restrict__ b_time,
                                              const float* __restrict__ w_in,
                                              const float* __restrict__ b_in,
                                              float* __restrict__ base) {
    int b = blockIdx.x, j = threadIdx.x;
    __shared__ float te[256];
    float tf = (float)t[b] / 200.0f;
    te[j] = fmaxf(tf * w_time[j] + b_time[j], 0.f);
    __syncthreads();
    float acc = b_in[j];
    for (int k = 0; k < 256; k++) acc = fmaf(te[k], w_in[(3 + k) * 256 + j], acc);
    base[b * 256 + j] = acc;
}

__global__ __launch_bounds__(256) void hinit_k(const float* __restrict__ x,
                                               const float* __restrict__ w_in,
                                               const float* __restrict__ base,
                                               float* __restrict__ h,
                                               float* __restrict__ h3) {
    long row = blockIdx.x;
    int b = (int)(row >> 10);
    int j = threadIdx.x;
    float x0 = x[row * 3 + 0], x1 = x[row * 3 + 1], x2 = x[row * 3 + 2];
    float v = base[b * 256 + j];
    v = fmaf(x0, w_in[j], v);
    v = fmaf(x1, w_in[256 + j], v);
    v = fmaf(x2, w_in[512 + j], v);
    v = fmaxf(v, 0.f);
    h[row * 256 + j] = v;
    if (j < 3) h3[row * 3 + j] = v;
}

// geo row -> hi/lo bf16 split, rn = sum(rep^2)
__global__ __launch_bounds__(256) void geo_k(const float* __restrict__ h3,
                                             u16* __restrict__ ghl,
                                             float* __restrict__ rn) {
    int bi = blockIdx.x;
    int b = bi >> 10, i = bi & 1023;
    const float* hb = h3 + (long)b * NN * 3;
    float ax = hb[i * 3 + 0], ay = hb[i * 3 + 1], az = hb[i * 3 + 2];
    u16* grow = ghl + (long)bi * 2048;
    float accs = 0.f;
    #pragma unroll
    for (int j0 = 0; j0 < NN; j0 += 256) {
        int j = j0 + threadIdx.x;
        float dx = hb[j * 3 + 0] - ax, dy = hb[j * 3 + 1] - ay, dz = hb[j * 3 + 2] - az;
        float d2 = dx * dx + dy * dy + dz * dz;
        float d = (d2 > 0.f) ? sqrtf(d2) : 0.f;
        u16 hi = (u16)bf16rne(d);
        float fhi = bf2f(hi);
        u16 lo = (u16)bf16rne(d - fhi);
        float rep = fhi + bf2f(lo);
        grow[j] = hi;
        grow[1024 + j] = lo;
        accs += rep * rep;
    }
    float tot = blockSum256(accs);
    if (threadIdx.x == 0) rn[bi] = tot;
}

// transpose+cast all layer weights to bf16 (NxK "Bt" layout)
__global__ __launch_bounds__(256) void wtrans_k(const float* __restrict__ qkv_w,
                                                const float* __restrict__ ao_w,
                                                const float* __restrict__ fc1_w,
                                                const float* __restrict__ fc2_w,
                                                u16* __restrict__ qkv_wt,
                                                u16* __restrict__ ao_wt,
                                                u16* __restrict__ fc1_wt,
                                                u16* __restrict__ fc2_wt) {
    int type = blockIdx.z, lyr = blockIdx.y;
    int R, Cc;
    const float* src;
    u16* dst;
    if (type == 0) { R = 256; Cc = 768;  src = qkv_w + (long)lyr * R * Cc; dst = qkv_wt + (long)lyr * R * Cc; }
    else if (type == 1) { R = 256; Cc = 256; src = ao_w + (long)lyr * R * Cc; dst = ao_wt + (long)lyr * R * Cc; }
    else if (type == 2) { R = 256; Cc = 1024; src = fc1_w + (long)lyr * R * Cc; dst = fc1_wt + (long)lyr * R * Cc; }
    else { R = 1024; Cc = 256; src = fc2_w + (long)lyr * R * Cc; dst = fc2_wt + (long)lyr * R * Cc; }
    int tC = Cc >> 5, tR = R >> 5;
    int tile = blockIdx.x;
    if (tile >= tC * tR) return;
    int c0 = (tile % tC) << 5, r0 = (tile / tC) << 5;
    __shared__ float tf[32][33];
    int tx = threadIdx.x & 31, ty = threadIdx.x >> 5;
    #pragma unroll
    for (int i = 0; i < 4; i++) {
        int r = ty + 8 * i;
        tf[r][tx] = src[(long)(r0 + r) * Cc + c0 + tx];
    }
    __syncthreads();
    #pragma unroll
    for (int i = 0; i < 4; i++) {
        int c = ty + 8 * i;
        dst[(long)(c0 + c) * R + r0 + tx] = (u16)bf16rne(tf[tx][c]);
    }
}

// transpose v (bf16, stride 768 within qkv) -> vt[b][c][n] bf16
__global__ __launch_bounds__(256) void vtrans_k(const u16* __restrict__ v, u16* __restrict__ vt) {
    int b = blockIdx.z;
    int n0 = blockIdx.x << 5, c0 = blockIdx.y << 5;
    const u16* vb = v + (long)b * NN * 768;
    u16* vtb = vt + (long)b * NH * NN;
    __shared__ u16 tile[32][33];
    int tx = threadIdx.x & 31, ty = threadIdx.x >> 5;
    #pragma unroll
    for (int i = 0; i < 4; i++) {
        int n = ty + 8 * i;
        tile[n][tx] = vb[(long)(n0 + n) * 768 + c0 + tx];
    }
    __syncthreads();
    #pragma unroll
    for (int i = 0; i < 4; i++) {
        int c = ty + 8 * i;
        vtb[(long)(c0 + c) * NN + n0 + tx] = tile[tx][c];
    }
}

__global__ __launch_bounds__(256) void ln_k(float* __restrict__ X,
                                            const float* __restrict__ g,
                                            const float* __restrict__ b) {
    long row = blockIdx.x;
    float* p = X + row * NH;
    int t = threadIdx.x;
    float v = p[t];
    float mu = blockSum256(v) * (1.f / NH);
    float d = v - mu;
    float var = blockSum256(d * d) * (1.f / NH);
    p[t] = d * rsqrtf(var + 1e-5f) * g[t] + b[t];
}

__global__ __launch_bounds__(256) void out_k(const float* __restrict__ h,
                                             const float* __restrict__ w_out,
                                             const float* __restrict__ b_out,
                                             float* __restrict__ out) {
    long row = blockIdx.x;
    int wid = threadIdx.x >> 6, lane = threadIdx.x & 63;
    if (wid < 3) {
        float acc = 0.f;
        for (int k = lane; k < 256; k += 64) acc = fmaf(h[row * 256 + k], w_out[k * 3 + wid], acc);
        #pragma unroll
        for (int o = 32; o; o >>= 1) acc += __shfl_down(acc, o, 64);
        if (lane == 0) out[row * 3 + wid] = acc + b_out[wid];
    }
}

extern "C" void kernel_launch(void* const* d_in, const int* in_sizes, int n_in,
                              void* d_out, int out_size, void* d_ws, size_t ws_size,
                              hipStream_t stream) {
    const float* x      = (const float*)d_in[0];
    const int*   t      = (const int*)  d_in[1];
    const float* w_time = (const float*)d_in[3];
    const float* b_time = (const float*)d_in[4];
    const float* w_in   = (const float*)d_in[5];
    const float* b_in   = (const float*)d_in[6];
    const float* w_out  = (const float*)d_in[7];
    const float* b_out  = (const float*)d_in[8];
    const float* qkv_w  = (const float*)d_in[9];
    const float* qkv_b  = (const float*)d_in[10];
    const float* ao_w   = (const float*)d_in[11];
    const float* ao_b   = (const float*)d_in[12];
    const float* fc1_w  = (const float*)d_in[13];
    const float* fc1_b  = (const float*)d_in[14];
    const float* fc2_w  = (const float*)d_in[15];
    const float* fc2_b  = (const float*)d_in[16];
    const float* ln1_g  = (const float*)d_in[17];
    const float* ln1_b  = (const float*)d_in[18];
    const float* ln2_g  = (const float*)d_in[19];
    const float* ln2_b  = (const float*)d_in[20];
    float* out = (float*)d_out;

    char* W = (char*)d_ws;
    float* h     = (float*)(W);                          // 8 MB
    float* xb    = (float*)(W + (8ul << 20));            // 8 MB
    u16*   obuf  = (u16*)  (W + (16ul << 20));           // 4 MB bf16
    u16*   edist = (u16*)  (W + (56ul << 20));           // 16 MB bf16
    u16*   ghl   = (u16*)  (W + (72ul << 20));           // 32 MB bf16 (hi|lo)
    u16*   qkvb  = (u16*)  (W + (72ul << 20));           // 12 MB bf16 (aliases ghl)
    u16*   f1    = (u16*)  (W + (84ul << 20));           // 16 MB bf16
    u16*   vt    = (u16*)  (W + (104ul << 20));          // 4 MB bf16
    u16*   wts   = (u16*)  (W + (108ul << 20));          // 4.5 MB bf16
    u16* qkv_wt = wts;                // 3 * 196608
    u16* ao_wt  = wts + 589824;       // 3 * 65536
    u16* fc1_wt = wts + 786432;       // 3 * 262144
    u16* fc2_wt = wts + 1572864;      // 3 * 262144
    float* base = (float*)(W + (114ul << 20));
    float* rn   = base + 2048;
    float* h3   = rn + 8192;

    const float scale = 1.0f / 16.0f;

    base_k<<<NB, 256, 0, stream>>>(t, w_time, b_time, w_in, b_in, base);
    hinit_k<<<NB * NN, 256, 0, stream>>>(x, w_in, base, h, h3);
    geo_k<<<NB * NN, 256, 0, stream>>>(h3, ghl, rn);
    wtrans_k<<<dim3(256, NL, 4), 256, 0, stream>>>(qkv_w, ao_w, fc1_w, fc2_w,
                                                   qkv_wt, ao_wt, fc1_wt, fc2_wt);
    // edist = exp(-cdist(geo,geo)): symmetric -> 36 lower-tri tiles, K=3072 aug
    gemm_mfma<EPI_EDIST, true, true, true, 3><<<dim3(36, 1, 8), 256, 0, stream>>>(
        ghl, 2048, (long)NN * 2048, ghl, 2048, (long)NN * 2048,
        edist, NN, (long)NN * NN, 3072, rn, NN, nullptr, 0);

    for (int l = 0; l < NL; ++l) {
        // qkv (bf16 out): h @ qkv_wt[l]^T
        gemm_mfma<EPI_BIAS, false, false, true, 2><<<dim3(6, 64, 1), 256, 0, stream>>>(
            h, NH, 0, qkv_wt + (long)l * 196608, NH, 0, qkvb, 768, 0,
            NH, qkv_b + l * 768, 0, nullptr, 0);
        vtrans_k<<<dim3(32, 8, NB), 256, 0, stream>>>(qkvb + 512, vt);
        // fused attention -> obuf bf16
        flash_k<<<dim3(32, 8), 512, 0, stream>>>(qkvb, vt, edist, obuf, scale);
        // xb = O @ ao_wt^T + ao_b + h
        gemm_mfma<EPI_BIAS_RESID, true, false, false, 2><<<dim3(2, 64, 1), 256, 0, stream>>>(
            obuf, NH, 0, ao_wt + (long)l * 65536, NH, 0, xb, NH, 0,
            NH, ao_b + l * NH, 0, h, NH);
        ln_k<<<NB * NN, 256, 0, stream>>>(xb, ln1_g + l * NH, ln1_b + l * NH);
        // f1 = relu(xb @ fc1_wt^T + b)  (bf16 out)
        gemm_mfma<EPI_BIAS_RELU, false, false, true, 2><<<dim3(8, 64, 1), 256, 0, stream>>>(
            xb, NH, 0, fc1_wt + (long)l * 262144, NH, 0, f1, 1024, 0,
            NH, fc1_b + l * 1024, 0, nullptr, 0);
        // h = relu(f1 @ fc2_wt^T + b) + xb
        gemm_mfma<EPI_BIAS_RELU_RESID, true, false, false, 2><<<dim3(2, 64, 1), 256, 0, stream>>>(
            f1, 1024, 0, fc2_wt + (long)l * 262144, 1024, 0, h, NH, 0,
            1024, fc2_b + l * NH, 0, xb, NH);
        ln_k<<<NB * NN, 256, 0, stream>>>(h, ln2_g + l * NH, ln2_b + l * NH);
    }
    out_k<<<NB * NN, 256, 0, stream>>>(h, w_out, b_out, out);
}

// Round 5
// 381.405 us; speedup vs baseline: 5.0532x; 1.2533x over previous
//
#include <hip/hip_runtime.h>
#include <math.h>

#define NB 8
#define NN 1024
#define NH 256
#define NL 3

typedef unsigned short u16;
typedef __bf16 bf16x8 __attribute__((ext_vector_type(8)));
typedef float f32x4 __attribute__((ext_vector_type(4)));

constexpr int EPI_BIAS_RELU = 2, EPI_BIAS_RELU_RESID = 3,
              EPI_BIAS_RESID = 4, EPI_EDIST = 5, EPI_QKV = 6;

__device__ __forceinline__ unsigned bf16rne(float f) {
    unsigned u = __float_as_uint(f);
    return (u + 0x7fffu + ((u >> 16) & 1u)) >> 16;
}
__device__ __forceinline__ unsigned bfpair(float a, float b) {
    return bf16rne(a) | (bf16rne(b) << 16);
}
__device__ __forceinline__ float bf2f(u16 h) {
    unsigned u = ((unsigned)h) << 16;
    return __uint_as_float(u);
}

__device__ __forceinline__ float blockSum256(float v) {
    __shared__ float sm[4];
    #pragma unroll
    for (int o = 32; o; o >>= 1) v += __shfl_down(v, o, 64);
    int lane = threadIdx.x & 63, wid = threadIdx.x >> 6;
    if (lane == 0) sm[wid] = v;
    __syncthreads();
    if (threadIdx.x == 0) sm[0] = sm[0] + sm[1] + sm[2] + sm[3];
    __syncthreads();
    float r = sm[0];
    __syncthreads();
    return r;
}

// ====== bf16 MFMA GEMM: MTx128 tile (MT=128 or 64), BK=64, 256 thr, 4 waves ==
// C = A @ Bt^T. A: MxK row-major bf16. Bt: NxK row-major bf16.
// SWZ: 2 chunked (z=1 grids, blocks%8==0), 3 triangular-symmetric batch-pinned
//      (edist: grid (72,1,8), 64-row tiles, writes transposed tile if below diag).
template <int EPI, bool AUG, bool OBF, int SWZ, int MT>
__global__ __launch_bounds__(256) void gemm_mfma(
    const u16* __restrict__ A, int lda, long sA,
    const u16* __restrict__ Bt, int ldb, long sB,
    void* __restrict__ C, int ldc, long sC,
    int K,
    const float* __restrict__ bias, long sBias,
    const float* __restrict__ resid, int ldr,
    u16* __restrict__ vtout)
{
    constexpr int MF = MT / 32;          // acc rows of frags: 4 or 2
    constexpr int ASZ = MT * 8;          // A chunk count
    __shared__ uint4 sm4[ASZ + 1024];
    const int tid = threadIdx.x;

    int bx = blockIdx.x, by = blockIdx.y, bz = blockIdx.z;
    bool trans = false;
    if (SWZ == 2) {
        int gx = gridDim.x;
        int T = gx * gridDim.y;
        int lid = bx + gx * by;
        int nl = (lid & 7) * (T >> 3) + (lid >> 3);
        bx = nl % gx; by = nl / gx;
    } else if (SWZ == 3) {
        int lid = bx + gridDim.x * bz;   // grid (72,1,8)
        bz = lid & 7;
        int idx = lid >> 3;              // 0..71
        int j = 0;
        while (idx >= 16 - 2 * j) { idx -= 16 - 2 * j; j++; }
        by = 2 * j + idx;                // 64-row tile index, by >= 2*bx
        bx = j;
        trans = (by >= 2 * bx + 2);
    }
    const int z = bz;
    const int row0 = by * MT, col0 = bx * 128;

    f32x4 acc[MF][4];
    #pragma unroll
    for (int m = 0; m < MF; m++)
        #pragma unroll
        for (int n = 0; n < 4; n++) acc[m][n] = (f32x4){0.f, 0.f, 0.f, 0.f};

    const int l = tid & 63, wid = tid >> 6;
    const int wr = wid >> 1, wc = wid & 1;
    const int lrow = l & 15, lgrp = l >> 4;

    for (int k0 = 0; k0 < K; k0 += 64) {
        int kk = k0, aOff = 0, bOff = 0;
        if (AUG) {
            int seg = k0 >> 10;
            kk = k0 & 1023;
            aOff = (seg == 2) ? 1024 : 0;
            bOff = (seg == 1) ? 1024 : 0;
        }
        if (MT == 128) {
            const int srow = tid >> 1, half = tid & 1, cb = half * 4, swz = srow & 7;
            const u16* Ap = A + (long)z * sA + (long)(row0 + srow) * lda + kk + aOff + half * 32;
            uint4 a0 = *(const uint4*)(Ap + 0),  a1 = *(const uint4*)(Ap + 8);
            uint4 a2 = *(const uint4*)(Ap + 16), a3 = *(const uint4*)(Ap + 24);
            sm4[srow * 8 + ((cb + 0) ^ swz)] = a0;
            sm4[srow * 8 + ((cb + 1) ^ swz)] = a1;
            sm4[srow * 8 + ((cb + 2) ^ swz)] = a2;
            sm4[srow * 8 + ((cb + 3) ^ swz)] = a3;
        } else {
            const int arow = tid >> 2, aq = tid & 3, swz = arow & 7;
            const u16* Ap = A + (long)z * sA + (long)(row0 + arow) * lda + kk + aOff + aq * 16;
            uint4 a0 = *(const uint4*)(Ap + 0), a1 = *(const uint4*)(Ap + 8);
            sm4[arow * 8 + ((aq * 2 + 0) ^ swz)] = a0;
            sm4[arow * 8 + ((aq * 2 + 1) ^ swz)] = a1;
        }
        {
            const int brow = tid >> 1, bq = tid & 1, cb = bq * 4, swz = brow & 7;
            const u16* Bp = Bt + (long)z * sB + (long)(col0 + brow) * ldb + kk + bOff + bq * 32;
            uint4 b0 = *(const uint4*)(Bp + 0),  b1 = *(const uint4*)(Bp + 8);
            uint4 b2 = *(const uint4*)(Bp + 16), b3 = *(const uint4*)(Bp + 24);
            sm4[ASZ + brow * 8 + ((cb + 0) ^ swz)] = b0;
            sm4[ASZ + brow * 8 + ((cb + 1) ^ swz)] = b1;
            sm4[ASZ + brow * 8 + ((cb + 2) ^ swz)] = b2;
            sm4[ASZ + brow * 8 + ((cb + 3) ^ swz)] = b3;
        }
        __syncthreads();

        #pragma unroll
        for (int ks = 0; ks < 2; ks++) {
            int c = ks * 4 + lgrp;
            bf16x8 a[MF], b[4];
            #pragma unroll
            for (int m = 0; m < MF; m++) {
                int r = wr * (MT / 2) + m * 16 + lrow;
                a[m] = __builtin_bit_cast(bf16x8, sm4[r * 8 + (c ^ (r & 7))]);
            }
            #pragma unroll
            for (int n = 0; n < 4; n++) {
                int r = wc * 64 + n * 16 + lrow;
                b[n] = __builtin_bit_cast(bf16x8, sm4[ASZ + r * 8 + (c ^ (r & 7))]);
            }
            #pragma unroll
            for (int m = 0; m < MF; m++)
                #pragma unroll
                for (int n = 0; n < 4; n++)
                    acc[m][n] = __builtin_amdgcn_mfma_f32_16x16x32_bf16(a[m], b[n], acc[m][n], 0, 0, 0);
        }
        __syncthreads();
    }

    // epilogue: C/D layout col = lane&15, row = 4*(lane>>4)+reg
    #pragma unroll
    for (int m = 0; m < MF; m++) {
        #pragma unroll
        for (int n = 0; n < 4; n++) {
            int rbase = row0 + wr * (MT / 2) + m * 16 + lgrp * 4;
            int cc = col0 + wc * 64 + n * 16 + lrow;
            float bv = 0.f;
            if (EPI == EPI_QKV || EPI == EPI_BIAS_RELU || EPI == EPI_BIAS_RELU_RESID || EPI == EPI_BIAS_RESID)
                bv = bias[cc];
            float vals[4];
            #pragma unroll
            for (int reg = 0; reg < 4; reg++) {
                long r = rbase + reg;
                float v = acc[m][n][reg];
                if (EPI == EPI_QKV) v += bv;
                else if (EPI == EPI_BIAS_RELU) v = fmaxf(v + bv, 0.f);
                else if (EPI == EPI_BIAS_RELU_RESID) v = fmaxf(v + bv, 0.f) + resid[r * ldr + cc];
                else if (EPI == EPI_BIAS_RESID) v = v + bv + resid[r * ldr + cc];
                else if (EPI == EPI_EDIST) {
                    const float* rnb = bias + (long)z * sBias;
                    float d2 = fmaxf(rnb[r] + rnb[cc] - 2.f * v, 0.f);
                    v = expf(-sqrtf(d2));
                }
                vals[reg] = v;
                if (OBF) ((u16*)C)[(long)z * sC + r * ldc + cc] = (u16)bf16rne(v);
                else     ((float*)C)[(long)z * sC + r * ldc + cc] = v;
            }
            if (EPI == EPI_EDIST && SWZ == 3 && trans) {
                uint2 tv;
                tv.x = bfpair(vals[0], vals[1]);
                tv.y = bfpair(vals[2], vals[3]);
                *(uint2*)&((u16*)C)[(long)z * sC + (long)cc * ldc + rbase] = tv;
            }
            if (EPI == EPI_QKV && cc >= 512) {
                // fused v-transpose: vt[b][c][n] bf16
                int b = rbase >> 10;
                uint2 tv;
                tv.x = bfpair(vals[0], vals[1]);
                tv.y = bfpair(vals[2], vals[3]);
                *(uint2*)&vtout[(long)b * NH * NN + (long)(cc - 512) * NN + (rbase & 1023)] = tv;
            }
        }
    }
}

// ============ flash attention: QBLK=32, KCHUNK=128, 512 thr (8 waves) ========
__global__ __launch_bounds__(512) void flash_k(
    const u16* __restrict__ qkv,    // [b][1024][768] bf16 (q +0, k +256)
    const u16* __restrict__ vt,     // [b][256][1024] bf16
    const u16* __restrict__ edist,  // [b][1024][1024] bf16
    u16* __restrict__ obuf,         // [b][1024][256] bf16
    float scale)
{
    __shared__ uint4 Ks[128][32];
    __shared__ uint4 Vts[256][16];
    __shared__ __align__(16) u16 Es[32][136];
    __shared__ __align__(16) u16 Ps[32][136];
    __shared__ float rs[32][8];

    const int tid = threadIdx.x;
    const int l = tid & 63, w = tid >> 6;
    const int g = l >> 4, lr = l & 15;

    int lid = blockIdx.x + gridDim.x * blockIdx.y;   // grid (32, 8)
    const int b = lid & 7;
    const int q0 = (lid >> 3) * 32;

    const u16* qkvb = qkv + (long)b * NN * 768;
    const u16* vtb  = vt + (long)b * NH * NN;
    const u16* eb   = edist + (long)b * NN * NN;

    uint4 qf[2][8];
    #pragma unroll
    for (int m = 0; m < 2; m++)
        #pragma unroll
        for (int ks = 0; ks < 8; ks++)
            qf[m][ks] = *(const uint4*)(qkvb + (long)(q0 + 16 * m + lr) * 768 + 32 * ks + 8 * g);

    f32x4 oacc[2][2];
    #pragma unroll
    for (int m = 0; m < 2; m++)
        #pragma unroll
        for (int nf = 0; nf < 2; nf++) oacc[m][nf] = (f32x4){0.f, 0.f, 0.f, 0.f};
    float rsum[2][4] = {{0.f, 0.f, 0.f, 0.f}, {0.f, 0.f, 0.f, 0.f}};

    for (int n0 = 0; n0 < NN; n0 += 128) {
        #pragma unroll
        for (int i = 0; i < 8; i++) {
            int idx = tid + 512 * i;
            int row = idx >> 5, ch = idx & 31;
            Ks[row][ch ^ (row & 7)] = *(const uint4*)(qkvb + (long)(n0 + row) * 768 + 256 + ch * 8);
        }
        #pragma unroll
        for (int i = 0; i < 8; i++) {
            int idx = tid + 512 * i;
            int c = idx >> 4, ch = idx & 15;
            Vts[c][(ch & 8) | ((ch & 7) ^ (c & 7))] = *(const uint4*)(vtb + (long)c * NN + n0 + ch * 8);
        }
        {
            int r = tid >> 4, ch = tid & 15;
            *(uint4*)&Es[r][ch * 8] = *(const uint4*)(eb + (long)(q0 + r) * NN + n0 + ch * 8);
        }
        __syncthreads();

        f32x4 s[2];
        s[0] = (f32x4){0.f, 0.f, 0.f, 0.f};
        s[1] = (f32x4){0.f, 0.f, 0.f, 0.f};
        const int krow = w * 16 + lr;
        #pragma unroll
        for (int ks = 0; ks < 8; ks++) {
            bf16x8 kf = __builtin_bit_cast(bf16x8, Ks[krow][(4 * ks + g) ^ (krow & 7)]);
            s[0] = __builtin_amdgcn_mfma_f32_16x16x32_bf16(__builtin_bit_cast(bf16x8, qf[0][ks]), kf, s[0], 0, 0, 0);
            s[1] = __builtin_amdgcn_mfma_f32_16x16x32_bf16(__builtin_bit_cast(bf16x8, qf[1][ks]), kf, s[1], 0, 0, 0);
        }
        #pragma unroll
        for (int m = 0; m < 2; m++)
            #pragma unroll
            for (int reg = 0; reg < 4; reg++) {
                int q = 16 * m + 4 * g + reg;
                int kc = w * 16 + lr;
                float p = expf(s[m][reg] * scale * bf2f(Es[q][kc]));
                rsum[m][reg] += p;
                Ps[q][kc] = (u16)bf16rne(p);
            }
        __syncthreads();
        #pragma unroll
        for (int ks = 0; ks < 4; ks++) {
            bf16x8 pa[2], vb[2];
            #pragma unroll
            for (int m = 0; m < 2; m++)
                pa[m] = __builtin_bit_cast(bf16x8, *(const uint4*)&Ps[16 * m + lr][32 * ks + 8 * g]);
            #pragma unroll
            for (int nf = 0; nf < 2; nf++) {
                int c = w * 32 + nf * 16 + lr;
                int ch = 4 * ks + g;
                vb[nf] = __builtin_bit_cast(bf16x8, Vts[c][(ch & 8) | ((ch & 7) ^ (c & 7))]);
            }
            #pragma unroll
            for (int m = 0; m < 2; m++)
                #pragma unroll
                for (int nf = 0; nf < 2; nf++)
                    oacc[m][nf] = __builtin_amdgcn_mfma_f32_16x16x32_bf16(pa[m], vb[nf], oacc[m][nf], 0, 0, 0);
        }
        __syncthreads();
    }

    #pragma unroll
    for (int m = 0; m < 2; m++)
        #pragma unroll
        for (int reg = 0; reg < 4; reg++) {
            float v = rsum[m][reg];
            v += __shfl_xor(v, 1); v += __shfl_xor(v, 2);
            v += __shfl_xor(v, 4); v += __shfl_xor(v, 8);
            rsum[m][reg] = v;
        }
    if (lr == 0) {
        #pragma unroll
        for (int m = 0; m < 2; m++)
            #pragma unroll
            for (int reg = 0; reg < 4; reg++)
                rs[16 * m + 4 * g + reg][w] = rsum[m][reg];
    }
    __syncthreads();
    #pragma unroll
    for (int m = 0; m < 2; m++) {
        #pragma unroll
        for (int reg = 0; reg < 4; reg++) {
            int q = 16 * m + 4 * g + reg;
            float t = 0.f;
            #pragma unroll
            for (int j = 0; j < 8; j++) t += rs[q][j];
            float inv = 1.f / t;
            #pragma unroll
            for (int nf = 0; nf < 2; nf++) {
                int c = w * 32 + nf * 16 + lr;
                obuf[(long)b * NN * NH + (long)(q0 + q) * NH + c] = (u16)bf16rne(oacc[m][nf][reg] * inv);
            }
        }
    }
}

__global__ __launch_bounds__(256) void base_k(const int* __restrict__ t,
                                              const float* __restrict__ w_time,
                                              const float* __restrict__ b_time,
                                              const float* __restrict__ w_in,
                                              const float* __restrict__ b_in,
                                              float* __restrict__ base) {
    int b = blockIdx.x, j = threadIdx.x;
    __shared__ float te[256];
    float tf = (float)t[b] / 200.0f;
    te[j] = fmaxf(tf * w_time[j] + b_time[j], 0.f);
    __syncthreads();
    float acc = b_in[j];
    for (int k = 0; k < 256; k++) acc = fmaf(te[k], w_in[(3 + k) * 256 + j], acc);
    base[b * 256 + j] = acc;
}

__global__ __launch_bounds__(256) void hinit_k(const float* __restrict__ x,
                                               const float* __restrict__ w_in,
                                               const float* __restrict__ base,
                                               float* __restrict__ h,
                                               u16* __restrict__ hbf,
                                               float* __restrict__ h3) {
    long row = blockIdx.x;
    int b = (int)(row >> 10);
    int j = threadIdx.x;
    float x0 = x[row * 3 + 0], x1 = x[row * 3 + 1], x2 = x[row * 3 + 2];
    float v = base[b * 256 + j];
    v = fmaf(x0, w_in[j], v);
    v = fmaf(x1, w_in[256 + j], v);
    v = fmaf(x2, w_in[512 + j], v);
    v = fmaxf(v, 0.f);
    h[row * 256 + j] = v;
    hbf[row * 256 + j] = (u16)bf16rne(v);
    if (j < 3) h3[row * 3 + j] = v;
}

__global__ __launch_bounds__(256) void geo_k(const float* __restrict__ h3,
                                             u16* __restrict__ ghl,
                                             float* __restrict__ rn) {
    int bi = blockIdx.x;
    int b = bi >> 10, i = bi & 1023;
    const float* hb = h3 + (long)b * NN * 3;
    float ax = hb[i * 3 + 0], ay = hb[i * 3 + 1], az = hb[i * 3 + 2];
    u16* grow = ghl + (long)bi * 2048;
    float accs = 0.f;
    #pragma unroll
    for (int j0 = 0; j0 < NN; j0 += 256) {
        int j = j0 + threadIdx.x;
        float dx = hb[j * 3 + 0] - ax, dy = hb[j * 3 + 1] - ay, dz = hb[j * 3 + 2] - az;
        float d2 = dx * dx + dy * dy + dz * dz;
        float d = (d2 > 0.f) ? sqrtf(d2) : 0.f;
        u16 hi = (u16)bf16rne(d);
        float fhi = bf2f(hi);
        u16 lo = (u16)bf16rne(d - fhi);
        float rep = fhi + bf2f(lo);
        grow[j] = hi;
        grow[1024 + j] = lo;
        accs += rep * rep;
    }
    float tot = blockSum256(accs);
    if (threadIdx.x == 0) rn[bi] = tot;
}

__global__ __launch_bounds__(256) void wtrans_k(const float* __restrict__ qkv_w,
                                                const float* __restrict__ ao_w,
                                                const float* __restrict__ fc1_w,
                                                const float* __restrict__ fc2_w,
                                                u16* __restrict__ qkv_wt,
                                                u16* __restrict__ ao_wt,
                                                u16* __restrict__ fc1_wt,
                                                u16* __restrict__ fc2_wt) {
    int type = blockIdx.z, lyr = blockIdx.y;
    int R, Cc;
    const float* src;
    u16* dst;
    if (type == 0) { R = 256; Cc = 768;  src = qkv_w + (long)lyr * R * Cc; dst = qkv_wt + (long)lyr * R * Cc; }
    else if (type == 1) { R = 256; Cc = 256; src = ao_w + (long)lyr * R * Cc; dst = ao_wt + (long)lyr * R * Cc; }
    else if (type == 2) { R = 256; Cc = 1024; src = fc1_w + (long)lyr * R * Cc; dst = fc1_wt + (long)lyr * R * Cc; }
    else { R = 1024; Cc = 256; src = fc2_w + (long)lyr * R * Cc; dst = fc2_wt + (long)lyr * R * Cc; }
    int tC = Cc >> 5, tR = R >> 5;
    int tile = blockIdx.x;
    if (tile >= tC * tR) return;
    int c0 = (tile % tC) << 5, r0 = (tile / tC) << 5;
    __shared__ float tf[32][33];
    int tx = threadIdx.x & 31, ty = threadIdx.x >> 5;
    #pragma unroll
    for (int i = 0; i < 4; i++) {
        int r = ty + 8 * i;
        tf[r][tx] = src[(long)(r0 + r) * Cc + c0 + tx];
    }
    __syncthreads();
    #pragma unroll
    for (int i = 0; i < 4; i++) {
        int c = ty + 8 * i;
        dst[(long)(c0 + c) * R + r0 + tx] = (u16)bf16rne(tf[tx][c]);
    }
}

// wave-per-row LayerNorm: X fp32 in-place + bf16 copy. grid 2048 x 256thr.
__global__ __launch_bounds__(256) void ln_k(float* __restrict__ X,
                                            u16* __restrict__ Xbf,
                                            const float* __restrict__ g,
                                            const float* __restrict__ b) {
    int wid = threadIdx.x >> 6, l = threadIdx.x & 63;
    long row = (long)blockIdx.x * 4 + wid;
    float* p = X + row * NH;
    float4 v = *(float4*)(p + l * 4);
    float s = v.x + v.y + v.z + v.w;
    #pragma unroll
    for (int o = 32; o; o >>= 1) s += __shfl_xor(s, o);
    float mu = s * (1.f / NH);
    float4 d = {v.x - mu, v.y - mu, v.z - mu, v.w - mu};
    float q = d.x * d.x + d.y * d.y + d.z * d.z + d.w * d.w;
    #pragma unroll
    for (int o = 32; o; o >>= 1) q += __shfl_xor(q, o);
    float rsd = rsqrtf(q * (1.f / NH) + 1e-5f);
    float4 g4 = *(const float4*)(g + l * 4);
    float4 b4 = *(const float4*)(b + l * 4);
    float4 o4;
    o4.x = d.x * rsd * g4.x + b4.x;
    o4.y = d.y * rsd * g4.y + b4.y;
    o4.z = d.z * rsd * g4.z + b4.z;
    o4.w = d.w * rsd * g4.w + b4.w;
    *(float4*)(p + l * 4) = o4;
    uint2 pk;
    pk.x = bfpair(o4.x, o4.y);
    pk.y = bfpair(o4.z, o4.w);
    *(uint2*)(Xbf + row * NH + l * 4) = pk;
}

__global__ __launch_bounds__(256) void out_k(const float* __restrict__ h,
                                             const float* __restrict__ w_out,
                                             const float* __restrict__ b_out,
                                             float* __restrict__ out) {
    long row = blockIdx.x;
    int wid = threadIdx.x >> 6, lane = threadIdx.x & 63;
    if (wid < 3) {
        float acc = 0.f;
        for (int k = lane; k < 256; k += 64) acc = fmaf(h[row * 256 + k], w_out[k * 3 + wid], acc);
        #pragma unroll
        for (int o = 32; o; o >>= 1) acc += __shfl_down(acc, o, 64);
        if (lane == 0) out[row * 3 + wid] = acc + b_out[wid];
    }
}

extern "C" void kernel_launch(void* const* d_in, const int* in_sizes, int n_in,
                              void* d_out, int out_size, void* d_ws, size_t ws_size,
                              hipStream_t stream) {
    const float* x      = (const float*)d_in[0];
    const int*   t      = (const int*)  d_in[1];
    const float* w_time = (const float*)d_in[3];
    const float* b_time = (const float*)d_in[4];
    const float* w_in   = (const float*)d_in[5];
    const float* b_in   = (const float*)d_in[6];
    const float* w_out  = (const float*)d_in[7];
    const float* b_out  = (const float*)d_in[8];
    const float* qkv_w  = (const float*)d_in[9];
    const float* qkv_b  = (const float*)d_in[10];
    const float* ao_w   = (const float*)d_in[11];
    const float* ao_b   = (const float*)d_in[12];
    const float* fc1_w  = (const float*)d_in[13];
    const float* fc1_b  = (const float*)d_in[14];
    const float* fc2_w  = (const float*)d_in[15];
    const float* fc2_b  = (const float*)d_in[16];
    const float* ln1_g  = (const float*)d_in[17];
    const float* ln1_b  = (const float*)d_in[18];
    const float* ln2_g  = (const float*)d_in[19];
    const float* ln2_b  = (const float*)d_in[20];
    float* out = (float*)d_out;

    char* W = (char*)d_ws;
    float* h     = (float*)(W);                          // 8 MB
    float* xb    = (float*)(W + (8ul << 20));            // 8 MB
    u16*   obuf  = (u16*)  (W + (16ul << 20));           // 4 MB
    u16*   hbf   = (u16*)  (W + (20ul << 20));           // 4 MB
    u16*   xbbf  = (u16*)  (W + (24ul << 20));           // 4 MB
    u16*   vt    = (u16*)  (W + (28ul << 20));           // 4 MB
    u16*   f1    = (u16*)  (W + (32ul << 20));           // 16 MB
    u16*   qkvb  = (u16*)  (W + (48ul << 20));           // 12 MB
    u16*   edist = (u16*)  (W + (60ul << 20));           // 16 MB
    u16*   ghl   = (u16*)  (W + (76ul << 20));           // 32 MB
    u16*   wts   = (u16*)  (W + (108ul << 20));          // 4.5 MB
    u16* qkv_wt = wts;                // 3 * 196608
    u16* ao_wt  = wts + 589824;       // 3 * 65536
    u16* fc1_wt = wts + 786432;       // 3 * 262144
    u16* fc2_wt = wts + 1572864;      // 3 * 262144
    float* base = (float*)(W + (114ul << 20));
    float* rn   = base + 2048;
    float* h3   = rn + 8192;

    const float scale = 1.0f / 16.0f;

    base_k<<<NB, 256, 0, stream>>>(t, w_time, b_time, w_in, b_in, base);
    hinit_k<<<NB * NN, 256, 0, stream>>>(x, w_in, base, h, hbf, h3);
    geo_k<<<NB * NN, 256, 0, stream>>>(h3, ghl, rn);
    wtrans_k<<<dim3(256, NL, 4), 256, 0, stream>>>(qkv_w, ao_w, fc1_w, fc2_w,
                                                   qkv_wt, ao_wt, fc1_wt, fc2_wt);
    // edist: symmetric, 64-row triangular tiles (72/batch), K=3072 aug, 576 blocks
    gemm_mfma<EPI_EDIST, true, true, 3, 64><<<dim3(72, 1, 8), 256, 0, stream>>>(
        ghl, 2048, (long)NN * 2048, ghl, 2048, (long)NN * 2048,
        edist, NN, (long)NN * NN, 3072, rn, NN, nullptr, 0, nullptr);

    for (int l = 0; l < NL; ++l) {
        // qkv (bf16 out) + fused v-transpose into vt
        gemm_mfma<EPI_QKV, false, true, 2, 128><<<dim3(6, 64, 1), 256, 0, stream>>>(
            hbf, NH, 0, qkv_wt + (long)l * 196608, NH, 0, qkvb, 768, 0,
            NH, qkv_b + l * 768, 0, nullptr, 0, vt);
        // fused attention -> obuf bf16
        flash_k<<<dim3(32, 8), 512, 0, stream>>>(qkvb, vt, edist, obuf, scale);
        // xb = O @ ao_wt^T + ao_b + h   (MT=64 -> 256 blocks)
        gemm_mfma<EPI_BIAS_RESID, false, false, 2, 64><<<dim3(2, 128, 1), 256, 0, stream>>>(
            obuf, NH, 0, ao_wt + (long)l * 65536, NH, 0, xb, NH, 0,
            NH, ao_b + l * NH, 0, h, NH, nullptr);
        ln_k<<<2048, 256, 0, stream>>>(xb, xbbf, ln1_g + l * NH, ln1_b + l * NH);
        // f1 = relu(xb @ fc1_wt^T + b)  (bf16 out)
        gemm_mfma<EPI_BIAS_RELU, false, true, 2, 128><<<dim3(8, 64, 1), 256, 0, stream>>>(
            xbbf, NH, 0, fc1_wt + (long)l * 262144, NH, 0, f1, 1024, 0,
            NH, fc1_b + l * 1024, 0, nullptr, 0, nullptr);
        // h = relu(f1 @ fc2_wt^T + b) + xb   (MT=64 -> 256 blocks)
        gemm_mfma<EPI_BIAS_RELU_RESID, false, false, 2, 64><<<dim3(2, 128, 1), 256, 0, stream>>>(
            f1, 1024, 0, fc2_wt + (long)l * 262144, 1024, 0, h, NH, 0,
            1024, fc2_b + l * NH, 0, xb, NH, nullptr);
        ln_k<<<2048, 256, 0, stream>>>(h, hbf, ln2_g + l * NH, ln2_b + l * NH);
    }
    out_k<<<NB * NN, 256, 0, stream>>>(h, w_out, b_out, out);
}

// Round 6
// 330.171 us; speedup vs baseline: 5.8373x; 1.1552x over previous
//
#include <hip/hip_runtime.h>
#include <math.h>

#define NB 8
#define NN 1024
#define NH 256
#define NL 3

typedef unsigned short u16;
typedef __bf16 bf16x8 __attribute__((ext_vector_type(8)));
typedef _Float16 f16x8 __attribute__((ext_vector_type(8)));
typedef float f32x4 __attribute__((ext_vector_type(4)));

constexpr int EPI_BIAS_RELU = 2, EPI_BIAS_RELU_RESID = 3, EPI_EDIST = 5, EPI_QKV = 6;

__device__ __forceinline__ unsigned bf16rne(float f) {
    unsigned u = __float_as_uint(f);
    return (u + 0x7fffu + ((u >> 16) & 1u)) >> 16;
}
__device__ __forceinline__ unsigned bfpair(float a, float b) {
    return bf16rne(a) | (bf16rne(b) << 16);
}
__device__ __forceinline__ float bf2f(u16 h) {
    unsigned u = ((unsigned)h) << 16;
    return __uint_as_float(u);
}

__device__ __forceinline__ float blockSum256(float v) {
    __shared__ float sm[4];
    #pragma unroll
    for (int o = 32; o; o >>= 1) v += __shfl_down(v, o, 64);
    int lane = threadIdx.x & 63, wid = threadIdx.x >> 6;
    if (lane == 0) sm[wid] = v;
    __syncthreads();
    if (threadIdx.x == 0) sm[0] = sm[0] + sm[1] + sm[2] + sm[3];
    __syncthreads();
    float r = sm[0];
    __syncthreads();
    return r;
}

// ====== MFMA GEMM: MTx128 tile (MT=128 or 64), BK=64, 256 thr, 4 waves ======
// C = A @ Bt^T. A: MxK row-major. Bt: NxK row-major. DT: 0=bf16, 1=fp16.
// SWZ: 2 chunked (z=1 grids, blocks%8==0), 3 triangular-symmetric batch-pinned.
template <int EPI, int DT, bool OBF, int SWZ, int MT>
__global__ __launch_bounds__(256) void gemm_mfma(
    const u16* __restrict__ A, int lda, long sA,
    const u16* __restrict__ Bt, int ldb, long sB,
    void* __restrict__ C, int ldc, long sC,
    int K,
    const float* __restrict__ bias, long sBias,
    const float* __restrict__ resid, int ldr,
    u16* __restrict__ vtout)
{
    constexpr int MF = MT / 32;
    constexpr int ASZ = MT * 8;
    __shared__ uint4 sm4[ASZ + 1024];
    const int tid = threadIdx.x;

    int bx = blockIdx.x, by = blockIdx.y, bz = blockIdx.z;
    bool trans = false;
    if (SWZ == 2) {
        int gx = gridDim.x;
        int T = gx * gridDim.y;
        int lid = bx + gx * by;
        int nl = (lid & 7) * (T >> 3) + (lid >> 3);
        bx = nl % gx; by = nl / gx;
    } else if (SWZ == 3) {
        int lid = bx + gridDim.x * bz;   // grid (72,1,8)
        bz = lid & 7;
        int idx = lid >> 3;
        int j = 0;
        while (idx >= 16 - 2 * j) { idx -= 16 - 2 * j; j++; }
        by = 2 * j + idx;
        bx = j;
        trans = (by >= 2 * bx + 2);
    }
    const int z = bz;
    const int row0 = by * MT, col0 = bx * 128;

    f32x4 acc[MF][4];
    #pragma unroll
    for (int m = 0; m < MF; m++)
        #pragma unroll
        for (int n = 0; n < 4; n++) acc[m][n] = (f32x4){0.f, 0.f, 0.f, 0.f};

    const int l = tid & 63, wid = tid >> 6;
    const int wr = wid >> 1, wc = wid & 1;
    const int lrow = l & 15, lgrp = l >> 4;

    for (int k0 = 0; k0 < K; k0 += 64) {
        if (MT == 128) {
            const int srow = tid >> 1, half = tid & 1, cb = half * 4, swz = srow & 7;
            const u16* Ap = A + (long)z * sA + (long)(row0 + srow) * lda + k0 + half * 32;
            uint4 a0 = *(const uint4*)(Ap + 0),  a1 = *(const uint4*)(Ap + 8);
            uint4 a2 = *(const uint4*)(Ap + 16), a3 = *(const uint4*)(Ap + 24);
            sm4[srow * 8 + ((cb + 0) ^ swz)] = a0;
            sm4[srow * 8 + ((cb + 1) ^ swz)] = a1;
            sm4[srow * 8 + ((cb + 2) ^ swz)] = a2;
            sm4[srow * 8 + ((cb + 3) ^ swz)] = a3;
        } else {
            const int arow = tid >> 2, aq = tid & 3, swz = arow & 7;
            const u16* Ap = A + (long)z * sA + (long)(row0 + arow) * lda + k0 + aq * 16;
            uint4 a0 = *(const uint4*)(Ap + 0), a1 = *(const uint4*)(Ap + 8);
            sm4[arow * 8 + ((aq * 2 + 0) ^ swz)] = a0;
            sm4[arow * 8 + ((aq * 2 + 1) ^ swz)] = a1;
        }
        {
            const int brow = tid >> 1, bq = tid & 1, cb = bq * 4, swz = brow & 7;
            const u16* Bp = Bt + (long)z * sB + (long)(col0 + brow) * ldb + k0 + bq * 32;
            uint4 b0 = *(const uint4*)(Bp + 0),  b1 = *(const uint4*)(Bp + 8);
            uint4 b2 = *(const uint4*)(Bp + 16), b3 = *(const uint4*)(Bp + 24);
            sm4[ASZ + brow * 8 + ((cb + 0) ^ swz)] = b0;
            sm4[ASZ + brow * 8 + ((cb + 1) ^ swz)] = b1;
            sm4[ASZ + brow * 8 + ((cb + 2) ^ swz)] = b2;
            sm4[ASZ + brow * 8 + ((cb + 3) ^ swz)] = b3;
        }
        __syncthreads();

        #pragma unroll
        for (int ks = 0; ks < 2; ks++) {
            int c = ks * 4 + lgrp;
            uint4 a[MF], b[4];
            #pragma unroll
            for (int m = 0; m < MF; m++) {
                int r = wr * (MT / 2) + m * 16 + lrow;
                a[m] = sm4[r * 8 + (c ^ (r & 7))];
            }
            #pragma unroll
            for (int n = 0; n < 4; n++) {
                int r = wc * 64 + n * 16 + lrow;
                b[n] = sm4[ASZ + r * 8 + (c ^ (r & 7))];
            }
            #pragma unroll
            for (int m = 0; m < MF; m++)
                #pragma unroll
                for (int n = 0; n < 4; n++) {
                    if (DT == 0)
                        acc[m][n] = __builtin_amdgcn_mfma_f32_16x16x32_bf16(
                            __builtin_bit_cast(bf16x8, a[m]), __builtin_bit_cast(bf16x8, b[n]), acc[m][n], 0, 0, 0);
                    else
                        acc[m][n] = __builtin_amdgcn_mfma_f32_16x16x32_f16(
                            __builtin_bit_cast(f16x8, a[m]), __builtin_bit_cast(f16x8, b[n]), acc[m][n], 0, 0, 0);
                }
        }
        __syncthreads();
    }

    // epilogue: C/D layout col = lane&15, row = 4*(lane>>4)+reg
    #pragma unroll
    for (int m = 0; m < MF; m++) {
        #pragma unroll
        for (int n = 0; n < 4; n++) {
            int rbase = row0 + wr * (MT / 2) + m * 16 + lgrp * 4;
            int cc = col0 + wc * 64 + n * 16 + lrow;
            float bv = 0.f;
            if (EPI == EPI_QKV || EPI == EPI_BIAS_RELU || EPI == EPI_BIAS_RELU_RESID)
                bv = bias[cc];
            float vals[4];
            #pragma unroll
            for (int reg = 0; reg < 4; reg++) {
                long r = rbase + reg;
                float v = acc[m][n][reg];
                if (EPI == EPI_QKV) v += bv;
                else if (EPI == EPI_BIAS_RELU) v = fmaxf(v + bv, 0.f);
                else if (EPI == EPI_BIAS_RELU_RESID) v = fmaxf(v + bv, 0.f) + resid[r * ldr + cc];
                else if (EPI == EPI_EDIST) {
                    const float* rnb = bias + (long)z * sBias;
                    float d2 = fmaxf(rnb[r] + rnb[cc] - 2.f * v, 0.f);
                    v = (r == cc) ? 1.f : expf(-sqrtf(d2));
                }
                vals[reg] = v;
                if (OBF) ((u16*)C)[(long)z * sC + r * ldc + cc] = (u16)bf16rne(v);
                else     ((float*)C)[(long)z * sC + r * ldc + cc] = v;
            }
            if (EPI == EPI_EDIST && SWZ == 3 && trans) {
                uint2 tv;
                tv.x = bfpair(vals[0], vals[1]);
                tv.y = bfpair(vals[2], vals[3]);
                *(uint2*)&((u16*)C)[(long)z * sC + (long)cc * ldc + rbase] = tv;
            }
            if (EPI == EPI_QKV && cc >= 512) {
                int b = rbase >> 10;
                uint2 tv;
                tv.x = bfpair(vals[0], vals[1]);
                tv.y = bfpair(vals[2], vals[3]);
                *(uint2*)&vtout[(long)b * NH * NN + (long)(cc - 512) * NN + (rbase & 1023)] = tv;
            }
        }
    }
}

// ==== flash attention + fused ao-proj + residual + LayerNorm1 ================
// grid (32,8) = 256 blocks, 512 thr (8 waves). Block = (batch b, 32 q-rows).
__global__ __launch_bounds__(512) void flash_k(
    const u16* __restrict__ qkv,    // [b][1024][768] bf16 (q +0, k +256)
    const u16* __restrict__ vt,     // [b][256][1024] bf16
    const u16* __restrict__ edist,  // [b][1024][1024] bf16
    const u16* __restrict__ aow,    // ao_wt layer: [256 j][256 c] bf16
    const float* __restrict__ aob,  // ao_b layer
    const float* __restrict__ hres, // h fp32 residual
    const float* __restrict__ g1,
    const float* __restrict__ b1,
    float* __restrict__ xb,         // out fp32
    u16* __restrict__ xbbf,         // out bf16
    float scale)
{
    __shared__ uint4 Ks[128][32];
    __shared__ uint4 Vts[256][16];
    __shared__ __align__(16) u16 Es[32][136];
    __shared__ __align__(16) u16 Ps[32][136];
    __shared__ float rs[32][8];
    __shared__ float lnA[32][8];
    __shared__ float lnB[32][8];

    const int tid = threadIdx.x;
    const int l = tid & 63, w = tid >> 6;
    const int g = l >> 4, lr = l & 15;

    int lid = blockIdx.x + gridDim.x * blockIdx.y;
    const int b = lid & 7;
    const int q0 = (lid >> 3) * 32;

    const u16* qkvb = qkv + (long)b * NN * 768;
    const u16* vtb  = vt + (long)b * NH * NN;
    const u16* eb   = edist + (long)b * NN * NN;

    uint4 qf[2][8];
    #pragma unroll
    for (int m = 0; m < 2; m++)
        #pragma unroll
        for (int ks = 0; ks < 8; ks++)
            qf[m][ks] = *(const uint4*)(qkvb + (long)(q0 + 16 * m + lr) * 768 + 32 * ks + 8 * g);

    f32x4 oacc[2][2];
    #pragma unroll
    for (int m = 0; m < 2; m++)
        #pragma unroll
        for (int nf = 0; nf < 2; nf++) oacc[m][nf] = (f32x4){0.f, 0.f, 0.f, 0.f};
    float rsum[2][4] = {{0.f, 0.f, 0.f, 0.f}, {0.f, 0.f, 0.f, 0.f}};

    for (int n0 = 0; n0 < NN; n0 += 128) {
        #pragma unroll
        for (int i = 0; i < 8; i++) {
            int idx = tid + 512 * i;
            int row = idx >> 5, ch = idx & 31;
            Ks[row][ch ^ (row & 7)] = *(const uint4*)(qkvb + (long)(n0 + row) * 768 + 256 + ch * 8);
        }
        #pragma unroll
        for (int i = 0; i < 8; i++) {
            int idx = tid + 512 * i;
            int c = idx >> 4, ch = idx & 15;
            Vts[c][(ch & 8) | ((ch & 7) ^ (c & 7))] = *(const uint4*)(vtb + (long)c * NN + n0 + ch * 8);
        }
        {
            int r = tid >> 4, ch = tid & 15;
            *(uint4*)&Es[r][ch * 8] = *(const uint4*)(eb + (long)(q0 + r) * NN + n0 + ch * 8);
        }
        __syncthreads();

        f32x4 s[2];
        s[0] = (f32x4){0.f, 0.f, 0.f, 0.f};
        s[1] = (f32x4){0.f, 0.f, 0.f, 0.f};
        const int krow = w * 16 + lr;
        #pragma unroll
        for (int ks = 0; ks < 8; ks++) {
            bf16x8 kf = __builtin_bit_cast(bf16x8, Ks[krow][(4 * ks + g) ^ (krow & 7)]);
            s[0] = __builtin_amdgcn_mfma_f32_16x16x32_bf16(__builtin_bit_cast(bf16x8, qf[0][ks]), kf, s[0], 0, 0, 0);
            s[1] = __builtin_amdgcn_mfma_f32_16x16x32_bf16(__builtin_bit_cast(bf16x8, qf[1][ks]), kf, s[1], 0, 0, 0);
        }
        #pragma unroll
        for (int m = 0; m < 2; m++)
            #pragma unroll
            for (int reg = 0; reg < 4; reg++) {
                int q = 16 * m + 4 * g + reg;
                int kc = w * 16 + lr;
                float p = expf(s[m][reg] * scale * bf2f(Es[q][kc]));
                rsum[m][reg] += p;
                Ps[q][kc] = (u16)bf16rne(p);
            }
        __syncthreads();
        #pragma unroll
        for (int ks = 0; ks < 4; ks++) {
            bf16x8 pa[2], vbf[2];
            #pragma unroll
            for (int m = 0; m < 2; m++)
                pa[m] = __builtin_bit_cast(bf16x8, *(const uint4*)&Ps[16 * m + lr][32 * ks + 8 * g]);
            #pragma unroll
            for (int nf = 0; nf < 2; nf++) {
                int c = w * 32 + nf * 16 + lr;
                int ch = 4 * ks + g;
                vbf[nf] = __builtin_bit_cast(bf16x8, Vts[c][(ch & 8) | ((ch & 7) ^ (c & 7))]);
            }
            #pragma unroll
            for (int m = 0; m < 2; m++)
                #pragma unroll
                for (int nf = 0; nf < 2; nf++)
                    oacc[m][nf] = __builtin_amdgcn_mfma_f32_16x16x32_bf16(pa[m], vbf[nf], oacc[m][nf], 0, 0, 0);
        }
        __syncthreads();
    }

    // rowsum reduction
    #pragma unroll
    for (int m = 0; m < 2; m++)
        #pragma unroll
        for (int reg = 0; reg < 4; reg++) {
            float v = rsum[m][reg];
            v += __shfl_xor(v, 1); v += __shfl_xor(v, 2);
            v += __shfl_xor(v, 4); v += __shfl_xor(v, 8);
            rsum[m][reg] = v;
        }
    if (lr == 0) {
        #pragma unroll
        for (int m = 0; m < 2; m++)
            #pragma unroll
            for (int reg = 0; reg < 4; reg++)
                rs[16 * m + 4 * g + reg][w] = rsum[m][reg];
    }
    __syncthreads();

    // normalized O -> LDS (overlay dead Ks region), bf16
    u16* Os = (u16*)Ks;   // [32][264]
    #pragma unroll
    for (int m = 0; m < 2; m++)
        #pragma unroll
        for (int reg = 0; reg < 4; reg++) {
            int q = 16 * m + 4 * g + reg;
            float t = 0.f;
            #pragma unroll
            for (int j = 0; j < 8; j++) t += rs[q][j];
            float inv = 1.f / t;
            #pragma unroll
            for (int nf = 0; nf < 2; nf++) {
                int c = w * 32 + nf * 16 + lr;
                Os[q * 264 + c] = (u16)bf16rne(oacc[m][nf][reg] * inv);
            }
        }
    __syncthreads();

    // ao GEMM: [32 q] x [256 j] = Os(32x256) @ aow(256j x 256c)^T
    f32x4 aacc[2][2];
    #pragma unroll
    for (int m = 0; m < 2; m++)
        #pragma unroll
        for (int nf = 0; nf < 2; nf++) aacc[m][nf] = (f32x4){0.f, 0.f, 0.f, 0.f};
    #pragma unroll
    for (int kc = 0; kc < 8; kc++) {
        bf16x8 pa[2], wb[2];
        #pragma unroll
        for (int m = 0; m < 2; m++)
            pa[m] = __builtin_bit_cast(bf16x8, *(const uint4*)&Os[(16 * m + lr) * 264 + kc * 32 + 8 * g]);
        #pragma unroll
        for (int nf = 0; nf < 2; nf++)
            wb[nf] = __builtin_bit_cast(bf16x8, *(const uint4*)(aow + (long)(32 * w + 16 * nf + lr) * 256 + kc * 32 + 8 * g));
        #pragma unroll
        for (int m = 0; m < 2; m++)
            #pragma unroll
            for (int nf = 0; nf < 2; nf++)
                aacc[m][nf] = __builtin_amdgcn_mfma_f32_16x16x32_bf16(pa[m], wb[nf], aacc[m][nf], 0, 0, 0);
    }

    // bias + residual
    int j0 = 32 * w + lr, j1 = 32 * w + 16 + lr;
    float aob0 = aob[j0], aob1 = aob[j1];
    float xv[2][2][4];
    #pragma unroll
    for (int m = 0; m < 2; m++)
        #pragma unroll
        for (int reg = 0; reg < 4; reg++) {
            int q = 16 * m + 4 * g + reg;
            long hr = ((long)b * NN + q0 + q) * NH;
            xv[m][0][reg] = aacc[m][0][reg] + aob0 + hres[hr + j0];
            xv[m][1][reg] = aacc[m][1][reg] + aob1 + hres[hr + j1];
        }

    // LN reductions: sum x, sum x^2 per row
    #pragma unroll
    for (int m = 0; m < 2; m++)
        #pragma unroll
        for (int reg = 0; reg < 4; reg++) {
            float s = xv[m][0][reg] + xv[m][1][reg];
            float s2 = xv[m][0][reg] * xv[m][0][reg] + xv[m][1][reg] * xv[m][1][reg];
            s  += __shfl_xor(s, 1);  s  += __shfl_xor(s, 2);  s  += __shfl_xor(s, 4);  s  += __shfl_xor(s, 8);
            s2 += __shfl_xor(s2, 1); s2 += __shfl_xor(s2, 2); s2 += __shfl_xor(s2, 4); s2 += __shfl_xor(s2, 8);
            if (lr == 0) {
                int q = 16 * m + 4 * g + reg;
                lnA[q][w] = s;
                lnB[q][w] = s2;
            }
        }
    __syncthreads();

    float g1v0 = g1[j0], g1v1 = g1[j1], b1v0 = b1[j0], b1v1 = b1[j1];
    #pragma unroll
    for (int m = 0; m < 2; m++)
        #pragma unroll
        for (int reg = 0; reg < 4; reg++) {
            int q = 16 * m + 4 * g + reg;
            float S = 0.f, S2 = 0.f;
            #pragma unroll
            for (int j = 0; j < 8; j++) { S += lnA[q][j]; S2 += lnB[q][j]; }
            float mu = S * (1.f / NH);
            float var = S2 * (1.f / NH) - mu * mu;
            float rsd = rsqrtf(var + 1e-5f);
            long hr = ((long)b * NN + q0 + q) * NH;
            float o0 = (xv[m][0][reg] - mu) * rsd * g1v0 + b1v0;
            float o1 = (xv[m][1][reg] - mu) * rsd * g1v1 + b1v1;
            xb[hr + j0] = o0;
            xb[hr + j1] = o1;
            xbbf[hr + j0] = (u16)bf16rne(o0);
            xbbf[hr + j1] = (u16)bf16rne(o1);
        }
}

__global__ __launch_bounds__(256) void base_k(const int* __restrict__ t,
                                              const float* __restrict__ w_time,
                                              const float* __restrict__ b_time,
                                              const float* __restrict__ w_in,
                                              const float* __restrict__ b_in,
                                              float* __restrict__ base) {
    int b = blockIdx.x, j = threadIdx.x;
    __shared__ float te[256];
    float tf = (float)t[b] / 200.0f;
    te[j] = fmaxf(tf * w_time[j] + b_time[j], 0.f);
    __syncthreads();
    float acc = b_in[j];
    for (int k = 0; k < 256; k++) acc = fmaf(te[k], w_in[(3 + k) * 256 + j], acc);
    base[b * 256 + j] = acc;
}

__global__ __launch_bounds__(256) void hinit_k(const float* __restrict__ x,
                                               const float* __restrict__ w_in,
                                               const float* __restrict__ base,
                                               float* __restrict__ h,
                                               u16* __restrict__ hbf,
                                               float* __restrict__ h3) {
    long row = blockIdx.x;
    int b = (int)(row >> 10);
    int j = threadIdx.x;
    float x0 = x[row * 3 + 0], x1 = x[row * 3 + 1], x2 = x[row * 3 + 2];
    float v = base[b * 256 + j];
    v = fmaf(x0, w_in[j], v);
    v = fmaf(x1, w_in[256 + j], v);
    v = fmaf(x2, w_in[512 + j], v);
    v = fmaxf(v, 0.f);
    h[row * 256 + j] = v;
    hbf[row * 256 + j] = (u16)bf16rne(v);
    if (j < 3) h3[row * 3 + j] = v;
}

// geo row -> fp16 bits, rn = sum of represented^2
__global__ __launch_bounds__(256) void geo_k(const float* __restrict__ h3,
                                             u16* __restrict__ gf,
                                             float* __restrict__ rn) {
    int bi = blockIdx.x;
    int b = bi >> 10, i = bi & 1023;
    const float* hb = h3 + (long)b * NN * 3;
    float ax = hb[i * 3 + 0], ay = hb[i * 3 + 1], az = hb[i * 3 + 2];
    u16* grow = gf + (long)bi * 1024;
    float accs = 0.f;
    #pragma unroll
    for (int j0 = 0; j0 < NN; j0 += 256) {
        int j = j0 + threadIdx.x;
        float dx = hb[j * 3 + 0] - ax, dy = hb[j * 3 + 1] - ay, dz = hb[j * 3 + 2] - az;
        float d2 = dx * dx + dy * dy + dz * dz;
        float d = (d2 > 0.f) ? sqrtf(d2) : 0.f;
        _Float16 hf = (_Float16)d;
        float rep = (float)hf;
        grow[j] = __builtin_bit_cast(u16, hf);
        accs += rep * rep;
    }
    float tot = blockSum256(accs);
    if (threadIdx.x == 0) rn[bi] = tot;
}

__global__ __launch_bounds__(256) void wtrans_k(const float* __restrict__ qkv_w,
                                                const float* __restrict__ ao_w,
                                                const float* __restrict__ fc1_w,
                                                const float* __restrict__ fc2_w,
                                                u16* __restrict__ qkv_wt,
                                                u16* __restrict__ ao_wt,
                                                u16* __restrict__ fc1_wt,
                                                u16* __restrict__ fc2_wt) {
    int type = blockIdx.z, lyr = blockIdx.y;
    int R, Cc;
    const float* src;
    u16* dst;
    if (type == 0) { R = 256; Cc = 768;  src = qkv_w + (long)lyr * R * Cc; dst = qkv_wt + (long)lyr * R * Cc; }
    else if (type == 1) { R = 256; Cc = 256; src = ao_w + (long)lyr * R * Cc; dst = ao_wt + (long)lyr * R * Cc; }
    else if (type == 2) { R = 256; Cc = 1024; src = fc1_w + (long)lyr * R * Cc; dst = fc1_wt + (long)lyr * R * Cc; }
    else { R = 1024; Cc = 256; src = fc2_w + (long)lyr * R * Cc; dst = fc2_wt + (long)lyr * R * Cc; }
    int tC = Cc >> 5, tR = R >> 5;
    int tile = blockIdx.x;
    if (tile >= tC * tR) return;
    int c0 = (tile % tC) << 5, r0 = (tile / tC) << 5;
    __shared__ float tf[32][33];
    int tx = threadIdx.x & 31, ty = threadIdx.x >> 5;
    #pragma unroll
    for (int i = 0; i < 4; i++) {
        int r = ty + 8 * i;
        tf[r][tx] = src[(long)(r0 + r) * Cc + c0 + tx];
    }
    __syncthreads();
    #pragma unroll
    for (int i = 0; i < 4; i++) {
        int c = ty + 8 * i;
        dst[(long)(c0 + c) * R + r0 + tx] = (u16)bf16rne(tf[tx][c]);
    }
}

// wave-per-row LayerNorm: X fp32 in-place + bf16 copy. grid 2048 x 256thr.
__global__ __launch_bounds__(256) void ln_k(float* __restrict__ X,
                                            u16* __restrict__ Xbf,
                                            const float* __restrict__ g,
                                            const float* __restrict__ b) {
    int wid = threadIdx.x >> 6, l = threadIdx.x & 63;
    long row = (long)blockIdx.x * 4 + wid;
    float* p = X + row * NH;
    float4 v = *(float4*)(p + l * 4);
    float s = v.x + v.y + v.z + v.w;
    #pragma unroll
    for (int o = 32; o; o >>= 1) s += __shfl_xor(s, o);
    float mu = s * (1.f / NH);
    float4 d = {v.x - mu, v.y - mu, v.z - mu, v.w - mu};
    float q = d.x * d.x + d.y * d.y + d.z * d.z + d.w * d.w;
    #pragma unroll
    for (int o = 32; o; o >>= 1) q += __shfl_xor(q, o);
    float rsd = rsqrtf(q * (1.f / NH) + 1e-5f);
    float4 g4 = *(const float4*)(g + l * 4);
    float4 b4 = *(const float4*)(b + l * 4);
    float4 o4;
    o4.x = d.x * rsd * g4.x + b4.x;
    o4.y = d.y * rsd * g4.y + b4.y;
    o4.z = d.z * rsd * g4.z + b4.z;
    o4.w = d.w * rsd * g4.w + b4.w;
    *(float4*)(p + l * 4) = o4;
    uint2 pk;
    pk.x = bfpair(o4.x, o4.y);
    pk.y = bfpair(o4.z, o4.w);
    *(uint2*)(Xbf + row * NH + l * 4) = pk;
}

__global__ __launch_bounds__(256) void out_k(const float* __restrict__ h,
                                             const float* __restrict__ w_out,
                                             const float* __restrict__ b_out,
                                             float* __restrict__ out) {
    long row = blockIdx.x;
    int wid = threadIdx.x >> 6, lane = threadIdx.x & 63;
    if (wid < 3) {
        float acc = 0.f;
        for (int k = lane; k < 256; k += 64) acc = fmaf(h[row * 256 + k], w_out[k * 3 + wid], acc);
        #pragma unroll
        for (int o = 32; o; o >>= 1) acc += __shfl_down(acc, o, 64);
        if (lane == 0) out[row * 3 + wid] = acc + b_out[wid];
    }
}

extern "C" void kernel_launch(void* const* d_in, const int* in_sizes, int n_in,
                              void* d_out, int out_size, void* d_ws, size_t ws_size,
                              hipStream_t stream) {
    const float* x      = (const float*)d_in[0];
    const int*   t      = (const int*)  d_in[1];
    const float* w_time = (const float*)d_in[3];
    const float* b_time = (const float*)d_in[4];
    const float* w_in   = (const float*)d_in[5];
    const float* b_in   = (const float*)d_in[6];
    const float* w_out  = (const float*)d_in[7];
    const float* b_out  = (const float*)d_in[8];
    const float* qkv_w  = (const float*)d_in[9];
    const float* qkv_b  = (const float*)d_in[10];
    const float* ao_w   = (const float*)d_in[11];
    const float* ao_b   = (const float*)d_in[12];
    const float* fc1_w  = (const float*)d_in[13];
    const float* fc1_b  = (const float*)d_in[14];
    const float* fc2_w  = (const float*)d_in[15];
    const float* fc2_b  = (const float*)d_in[16];
    const float* ln1_g  = (const float*)d_in[17];
    const float* ln1_b  = (const float*)d_in[18];
    const float* ln2_g  = (const float*)d_in[19];
    const float* ln2_b  = (const float*)d_in[20];
    float* out = (float*)d_out;

    char* W = (char*)d_ws;
    float* h     = (float*)(W);                          // 8 MB
    float* xb    = (float*)(W + (8ul << 20));            // 8 MB
    u16*   hbf   = (u16*)  (W + (16ul << 20));           // 4 MB
    u16*   xbbf  = (u16*)  (W + (20ul << 20));           // 4 MB
    u16*   vt    = (u16*)  (W + (24ul << 20));           // 4 MB
    u16*   f1    = (u16*)  (W + (28ul << 20));           // 16 MB
    u16*   qkvb  = (u16*)  (W + (44ul << 20));           // 12 MB
    u16*   edist = (u16*)  (W + (56ul << 20));           // 16 MB
    u16*   gf    = (u16*)  (W + (72ul << 20));           // 16 MB (fp16 geo)
    u16*   wts   = (u16*)  (W + (88ul << 20));           // 4.5 MB
    u16* qkv_wt = wts;                // 3 * 196608
    u16* ao_wt  = wts + 589824;       // 3 * 65536
    u16* fc1_wt = wts + 786432;       // 3 * 262144
    u16* fc2_wt = wts + 1572864;      // 3 * 262144
    float* base = (float*)(W + (94ul << 20));
    float* rn   = base + 2048;
    float* h3   = rn + 8192;

    const float scale = 1.0f / 16.0f;

    base_k<<<NB, 256, 0, stream>>>(t, w_time, b_time, w_in, b_in, base);
    hinit_k<<<NB * NN, 256, 0, stream>>>(x, w_in, base, h, hbf, h3);
    geo_k<<<NB * NN, 256, 0, stream>>>(h3, gf, rn);
    wtrans_k<<<dim3(256, NL, 4), 256, 0, stream>>>(qkv_w, ao_w, fc1_w, fc2_w,
                                                   qkv_wt, ao_wt, fc1_wt, fc2_wt);
    // edist: fp16 Gram, K=1024, symmetric 64-row triangular tiles (576 blocks)
    gemm_mfma<EPI_EDIST, 1, true, 3, 64><<<dim3(72, 1, 8), 256, 0, stream>>>(
        gf, 1024, (long)NN * 1024, gf, 1024, (long)NN * 1024,
        edist, NN, (long)NN * NN, 1024, rn, NN, nullptr, 0, nullptr);

    for (int l = 0; l < NL; ++l) {
        // qkv (bf16 out) + fused v-transpose into vt
        gemm_mfma<EPI_QKV, 0, true, 2, 128><<<dim3(6, 64, 1), 256, 0, stream>>>(
            hbf, NH, 0, qkv_wt + (long)l * 196608, NH, 0, qkvb, 768, 0,
            NH, qkv_b + l * 768, 0, nullptr, 0, vt);
        // fused attention + ao-proj + residual + LN1 -> xb / xbbf
        flash_k<<<dim3(32, 8), 512, 0, stream>>>(
            qkvb, vt, edist, ao_wt + (long)l * 65536, ao_b + l * NH,
            h, ln1_g + l * NH, ln1_b + l * NH, xb, xbbf, scale);
        // f1 = relu(xb @ fc1_wt^T + b)  (bf16 out)
        gemm_mfma<EPI_BIAS_RELU, 0, true, 2, 128><<<dim3(8, 64, 1), 256, 0, stream>>>(
            xbbf, NH, 0, fc1_wt + (long)l * 262144, NH, 0, f1, 1024, 0,
            NH, fc1_b + l * 1024, 0, nullptr, 0, nullptr);
        // h = relu(f1 @ fc2_wt^T + b) + xb   (MT=64 -> 256 blocks)
        gemm_mfma<EPI_BIAS_RELU_RESID, 0, false, 2, 64><<<dim3(2, 128, 1), 256, 0, stream>>>(
            f1, 1024, 0, fc2_wt + (long)l * 262144, 1024, 0, h, NH, 0,
            1024, fc2_b + l * NH, 0, xb, NH, nullptr);
        ln_k<<<2048, 256, 0, stream>>>(h, hbf, ln2_g + l * NH, ln2_b + l * NH);
    }
    out_k<<<NB * NN, 256, 0, stream>>>(h, w_out, b_out, out);
}